// Round 15
// baseline (483.315 us; speedup 1.0000x reference)
//
#include <hip/hip_runtime.h>
#include <stdint.h>

typedef _Float16 f16x8 __attribute__((ext_vector_type(8)));
typedef _Float16 f16x4 __attribute__((ext_vector_type(4)));
typedef float    f32x4 __attribute__((ext_vector_type(4)));

__device__ __forceinline__ void load16_lds(const _Float16* g, _Float16* l) {
    __builtin_amdgcn_global_load_lds(
        (const __attribute__((address_space(1))) void*)g,
        (__attribute__((address_space(3))) void*)l, 16, 0, 0);
}

// ---------------------------------------------------------------- fused casts
// blocks [0,18432): q/k/v/o f32->f16;  [18432,22528): guw interleave;
// [22528,26624): dwc permute;  26624: ones block.
__global__ __launch_bounds__(256) void k_castall(
    const float* __restrict__ q, const float* __restrict__ k,
    const float* __restrict__ v, const float* __restrict__ o,
    const float* __restrict__ eg, const float* __restrict__ eu,
    const float* __restrict__ edw,
    _Float16* __restrict__ qkvw, _Float16* __restrict__ ow,
    _Float16* __restrict__ guw, _Float16* __restrict__ dwc,
    _Float16* __restrict__ ones16)
{
    const int bid = blockIdx.x;
    if (bid < 18432) {
        size_t i = ((size_t)bid * 256 + threadIdx.x) * 4;
        const float* src; _Float16* dst;
        if (i < 8388608)        { src = q + i;             dst = qkvw + i; }
        else if (i < 9437184)   { src = k + (i - 8388608); dst = qkvw + i; }
        else if (i < 10485760)  { src = v + (i - 9437184); dst = qkvw + i; }
        else                    { src = o + (i - 10485760); dst = ow + (i - 10485760); }
        float4 x = *reinterpret_cast<const float4*>(src);
        f16x4 y = { (_Float16)x.x, (_Float16)x.y, (_Float16)x.z, (_Float16)x.w };
        *reinterpret_cast<f16x4*>(dst) = y;
    } else if (bid < 22528) {
        const int row = bid - 18432;
        const int e = row >> 8, rem = row & 255, half = rem >> 7, mi = rem & 127;
        const float* src = (half ? eu : eg) + ((size_t)(e * 128 + mi)) * 2048;
        const int c = threadIdx.x * 8;
        float4 v0 = *reinterpret_cast<const float4*>(src + c);
        float4 v1 = *reinterpret_cast<const float4*>(src + c + 4);
        f16x8 ov = { (_Float16)v0.x,(_Float16)v0.y,(_Float16)v0.z,(_Float16)v0.w,
                     (_Float16)v1.x,(_Float16)v1.y,(_Float16)v1.z,(_Float16)v1.w };
        *reinterpret_cast<f16x8*>(guw + (size_t)row * 2048 + c) = ov;
    } else if (bid < 26624) {
        int t = (bid - 22528) * 256 + threadIdx.x;
        int mi4 = (t & 31) * 4;
        int dm = (t >> 5) & 2047;
        int e = t >> 16;
        float4 vv = *reinterpret_cast<const float4*>(edw + (((size_t)e * 2048 + dm) << 7) + mi4);
        f16x4 ov = { (_Float16)vv.x, (_Float16)vv.y, (_Float16)vv.z, (_Float16)vv.w };
        *reinterpret_cast<f16x4*>(dwc + ((size_t)dm << 11) + e * 128 + mi4) = ov;
    } else {
        int i = threadIdx.x;
        _Float16 vv = (i < 16) ? (_Float16)1.0f : (_Float16)0.0f;
        f16x4 ov = { vv, vv, vv, vv };
        *reinterpret_cast<f16x4*>(ones16 + i * 4) = ov;
    }
}

// ---------------------------------------------------------------- rmsnorm (f16 out)
__global__ __launch_bounds__(256) void k_rmsnorm(
    const float* __restrict__ x, const float* __restrict__ w,
    _Float16* __restrict__ oh)
{
    const int row = blockIdx.x, tid = threadIdx.x;
    const float* xr = x + (size_t)row * 2048;
    float4 a = *reinterpret_cast<const float4*>(xr + tid * 8);
    float4 b = *reinterpret_cast<const float4*>(xr + tid * 8 + 4);
    float ss = a.x*a.x + a.y*a.y + a.z*a.z + a.w*a.w
             + b.x*b.x + b.y*b.y + b.z*b.z + b.w*b.w;
    #pragma unroll
    for (int m = 1; m < 64; m <<= 1) ss += __shfl_xor(ss, m);
    __shared__ float red[4];
    if ((tid & 63) == 0) red[tid >> 6] = ss;
    __syncthreads();
    float tot = red[0] + red[1] + red[2] + red[3];
    float r = rsqrtf(tot * (1.f / 2048.f) + 1e-6f);
    float4 wa = *reinterpret_cast<const float4*>(w + tid * 8);
    float4 wb = *reinterpret_cast<const float4*>(w + tid * 8 + 4);
    f16x8 hv = { (_Float16)(a.x*r*wa.x), (_Float16)(a.y*r*wa.y),
                 (_Float16)(a.z*r*wa.z), (_Float16)(a.w*r*wa.w),
                 (_Float16)(b.x*r*wb.x), (_Float16)(b.y*r*wb.y),
                 (_Float16)(b.z*r*wb.z), (_Float16)(b.w*r*wb.w) };
    *reinterpret_cast<f16x8*>(oh + (size_t)row * 2048 + tid * 8) = hv;
}

// ---------------------------------------------------------------- GEMM 128x128
__global__ __launch_bounds__(256) void k_gemm(
    const _Float16* __restrict__ A, int lda,
    const _Float16* __restrict__ W, int ldw,
    float* __restrict__ Cf, _Float16* __restrict__ Ch, int ldc,
    const float* __restrict__ resid, int K)
{
    __shared__ __align__(16) _Float16 As[3][128][32];
    __shared__ __align__(16) _Float16 Ws[3][128][32];
    const int r0 = blockIdx.x * 128, c0 = blockIdx.y * 128;
    const int tid = threadIdx.x, lane = tid & 63, wid = tid >> 6;
    const int wr = wid >> 1, wc = wid & 1;
    const int sr = lane >> 2;
    const int scs = ((lane & 3) ^ ((lane >> 3) & 3)) * 8;
    const int fr = lane & 15;
    const int rks = (((lane >> 4) ^ ((fr >> 1) & 3))) * 8;
    const f32x4 z4 = { 0.f, 0.f, 0.f, 0.f };
    f32x4 acc[4][4];
    #pragma unroll
    for (int i = 0; i < 4; i++)
        #pragma unroll
        for (int j = 0; j < 4; j++) acc[i][j] = z4;

    auto stage = [&](int bf, int k0) {
        #pragma unroll
        for (int i = 0; i < 2; i++) {
            int ch = wid * 2 + i;
            load16_lds(A + (size_t)(r0 + ch * 16 + sr) * lda + k0 + scs, &As[bf][ch * 16][0]);
            load16_lds(W + (size_t)(c0 + ch * 16 + sr) * ldw + k0 + scs, &Ws[bf][ch * 16][0]);
        }
    };

    const int nt = K >> 5;
    stage(0, 0);
    if (nt > 1) stage(1, 32);
    int cur = 0;
    for (int t = 0; t < nt; t++) {
        if (t < nt - 1) asm volatile("s_waitcnt vmcnt(4)" ::: "memory");
        else            asm volatile("s_waitcnt vmcnt(0)" ::: "memory");
        __builtin_amdgcn_s_barrier();
        f16x8 af[4], bf4[4];
        #pragma unroll
        for (int i = 0; i < 4; i++)
            af[i] = *reinterpret_cast<const f16x8*>(&As[cur][wr * 64 + i * 16 + fr][rks]);
        #pragma unroll
        for (int j = 0; j < 4; j++)
            bf4[j] = *reinterpret_cast<const f16x8*>(&Ws[cur][wc * 64 + j * 16 + fr][rks]);
        if (t + 2 < nt) stage((t + 2) % 3, (t + 2) << 5);
        __builtin_amdgcn_s_setprio(1);
        #pragma unroll
        for (int i = 0; i < 4; i++)
            #pragma unroll
            for (int j = 0; j < 4; j++)
                acc[i][j] = __builtin_amdgcn_mfma_f32_16x16x32_f16(af[i], bf4[j], acc[i][j], 0, 0, 0);
        __builtin_amdgcn_s_setprio(0);
        cur = (cur + 1) % 3;
    }
    #pragma unroll
    for (int i = 0; i < 4; i++) {
        const int rowb = r0 + wr * 64 + i * 16 + (lane >> 4) * 4;
        #pragma unroll
        for (int j = 0; j < 4; j++) {
            const int col = c0 + wc * 64 + j * 16 + fr;
            #pragma unroll
            for (int r = 0; r < 4; r++) {
                size_t idx = (size_t)(rowb + r) * ldc + col;
                float v = acc[i][j][r];
                if (resid) v += resid[idx];
                if (Ch) Ch[idx] = (_Float16)v;
                else    Cf[idx] = v;
            }
        }
    }
}

// ---------------------------------------------------------------- GEMM 256x256, 8 waves
// gu-mode (wdense!=null): fused silu(g)*u*w_e epilogue -> ab.
__global__ __launch_bounds__(512, 2) void k_gemm8(
    const _Float16* __restrict__ A, int lda,
    const _Float16* __restrict__ W, int ldw,
    _Float16* __restrict__ Ch, int ldc, int K,
    const float* __restrict__ wdense, _Float16* __restrict__ ab)
{
    __shared__ __align__(16) _Float16 As[3][256][32];
    __shared__ __align__(16) _Float16 Ws[3][256][32];
    const int r0 = blockIdx.x * 256, c0 = blockIdx.y * 256;
    const int tid = threadIdx.x, lane = tid & 63, wid = tid >> 6;
    const int wr = wid >> 2, wc = wid & 3;
    const int rA = lane >> 2;
    const int scs = ((lane & 3) ^ ((lane >> 3) & 3)) * 8;
    const int fr = lane & 15, fg = lane >> 4;
    const int rks = (((lane >> 4) ^ ((fr >> 1) & 3))) * 8;
    const f32x4 z4 = { 0.f, 0.f, 0.f, 0.f };
    f32x4 acc[8][4];
    #pragma unroll
    for (int i = 0; i < 8; i++)
        #pragma unroll
        for (int j = 0; j < 4; j++) acc[i][j] = z4;

    auto stage = [&](int bf, int k0) {
        #pragma unroll
        for (int i = 0; i < 2; i++) {
            load16_lds(A + (size_t)(r0 + i * 128 + wid * 16 + rA) * lda + k0 + scs,
                       &As[bf][i * 128 + wid * 16][0]);
            load16_lds(W + (size_t)(c0 + i * 128 + wid * 16 + rA) * ldw + k0 + scs,
                       &Ws[bf][i * 128 + wid * 16][0]);
        }
    };

    const int nt = K >> 5;
    stage(0, 0);
    if (nt > 1) stage(1, 32);
    int cur = 0;
    for (int t = 0; t < nt; t++) {
        if (t < nt - 1) asm volatile("s_waitcnt vmcnt(4)" ::: "memory");
        else            asm volatile("s_waitcnt vmcnt(0)" ::: "memory");
        __builtin_amdgcn_s_barrier();
        f16x8 af[8], bf4[4];
        #pragma unroll
        for (int i = 0; i < 8; i++)
            af[i] = *reinterpret_cast<const f16x8*>(&As[cur][wr * 128 + i * 16 + fr][rks]);
        #pragma unroll
        for (int j = 0; j < 4; j++)
            bf4[j] = *reinterpret_cast<const f16x8*>(&Ws[cur][wc * 64 + j * 16 + fr][rks]);
        if (t + 2 < nt) stage((t + 2) % 3, (t + 2) << 5);
        __builtin_amdgcn_s_setprio(1);
        #pragma unroll
        for (int i = 0; i < 8; i++)
            #pragma unroll
            for (int j = 0; j < 4; j++)
                acc[i][j] = __builtin_amdgcn_mfma_f32_16x16x32_f16(af[i], bf4[j], acc[i][j], 0, 0, 0);
        __builtin_amdgcn_s_setprio(0);
        cur = (cur + 1) % 3;
    }

    if (!wdense) {
        #pragma unroll
        for (int i = 0; i < 8; i++) {
            const int rowb = r0 + wr * 128 + i * 16 + fg * 4;
            #pragma unroll
            for (int j = 0; j < 4; j++) {
                const int col = c0 + wc * 64 + j * 16 + fr;
                #pragma unroll
                for (int r = 0; r < 4; r++)
                    Ch[(size_t)(rowb + r) * ldc + col] = (_Float16)acc[i][j][r];
            }
        }
        return;
    }

    _Float16* LgA = &As[0][0][0];
    _Float16* LgB = &Ws[0][0][0];
    auto lgp = [&](int row, int mi) -> _Float16* {
        return ((row < 128) ? LgA : LgB) + (size_t)(row & 127) * 136 + mi;
    };
    const int e = blockIdx.y;
    __syncthreads();
    if (wc < 2) {
        #pragma unroll
        for (int i = 0; i < 8; i++) {
            const int row = wr * 128 + i * 16 + fg * 4;
            #pragma unroll
            for (int j = 0; j < 4; j++) {
                const int mi = wc * 64 + j * 16 + fr;
                #pragma unroll
                for (int r = 0; r < 4; r++)
                    *lgp(row + r, mi) = (_Float16)acc[i][j][r];
            }
        }
    }
    __syncthreads();
    if (wc >= 2) {
        #pragma unroll
        for (int i = 0; i < 8; i++) {
            const int row = wr * 128 + i * 16 + fg * 4;
            #pragma unroll
            for (int j = 0; j < 4; j++) {
                const int mi = (wc - 2) * 64 + j * 16 + fr;
                #pragma unroll
                for (int r = 0; r < 4; r++) {
                    float g = (float)*lgp(row + r, mi);
                    float sil = g / (1.f + __expf(-g));
                    *lgp(row + r, mi) = (_Float16)(sil * acc[i][j][r]);
                }
            }
        }
    }
    __syncthreads();
    #pragma unroll
    for (int pass = 0; pass < 8; pass++) {
        int cid = pass * 512 + tid;
        int row = cid >> 4, col8 = cid & 15;
        f16x8 v = *reinterpret_cast<const f16x8*>(
            ((row < 128) ? LgA : LgB) + (size_t)(row & 127) * 136 + col8 * 8);
        float wv = wdense[(size_t)e * 4096 + r0 + row];
        f16x8 o;
        #pragma unroll
        for (int j = 0; j < 8; j++) o[j] = (_Float16)((float)v[j] * wv);
        *reinterpret_cast<f16x8*>(ab + (size_t)(r0 + row) * 2048 + e * 128 + col8 * 8) = o;
    }
}

// ------------------------------------------- per-head RMSNorm + RoPE + V-transpose
// y<9: head work (u=y*4+widx). y==9 & x<512: V-transpose unit.
__global__ __launch_bounds__(256) void k_qkv_post(
    const _Float16* __restrict__ qkv,
    const float* __restrict__ cosb, const float* __restrict__ sinb,
    const float* __restrict__ qn_w, const float* __restrict__ kn_w,
    _Float16* __restrict__ qh, _Float16* __restrict__ kh,
    _Float16* __restrict__ vth)
{
    if (blockIdx.y == 9) {
        const int unit = blockIdx.x;
        if (unit >= 512) return;
        const int bkv = unit >> 5, rem = unit & 31;
        const int l0 = (rem >> 1) * 64, d0 = (rem & 1) * 64;
        const int b = bkv >> 2, kv = bkv & 3;
        __shared__ _Float16 T[64][72];
        const int t = threadIdx.x;
        const int r = t >> 3, c8 = (t & 7) * 8;
        #pragma unroll
        for (int rr = 0; rr < 2; rr++) {
            int l = l0 + r + rr * 32;
            *reinterpret_cast<f16x8*>(&T[r + rr * 32][c8]) =
                *reinterpret_cast<const f16x8*>(
                    qkv + (size_t)(b * 1024 + l) * 5120 + 4608 + kv * 128 + d0 + c8);
        }
        __syncthreads();
        #pragma unroll
        for (int rr = 0; rr < 2; rr++) {
            int d = d0 + r + rr * 32;
            f16x8 v;
            #pragma unroll
            for (int j = 0; j < 8; j++) v[j] = T[c8 + j][r + rr * 32];
            *reinterpret_cast<f16x8*>(vth + ((size_t)(bkv * 128 + d)) * 1024 + l0 + c8) = v;
        }
        return;
    }
    const int tok = blockIdx.x;
    const int u = blockIdx.y * 4 + (threadIdx.x >> 6);
    const int lane = threadIdx.x & 63;
    const int b = tok >> 10, l = tok & 1023;
    const float SCL = 0.12752887074166638f;   // 1/sqrt(128) * log2(e)
    const float c0 = cosb[(size_t)tok * 128 + lane];
    const float c1 = cosb[(size_t)tok * 128 + lane + 64];
    const float s0 = sinb[(size_t)tok * 128 + lane];
    const float s1 = sinb[(size_t)tok * 128 + lane + 64];
    if (u < 32) {
        const _Float16* base = qkv + (size_t)tok * 5120 + u * 128;
        float v0 = (float)base[lane], v1 = (float)base[lane + 64];
        float ss = v0 * v0 + v1 * v1;
        #pragma unroll
        for (int m = 1; m < 64; m <<= 1) ss += __shfl_xor(ss, m);
        float rms = rsqrtf(ss * (1.f / 128.f) + 1e-6f);
        float n0 = v0 * rms * qn_w[lane], n1 = v1 * rms * qn_w[lane + 64];
        _Float16* o = qh + (size_t)tok * 4096 + u * 128;
        o[lane]      = (_Float16)(SCL * (c0 * n0 - s0 * n1));
        o[lane + 64] = (_Float16)(SCL * (c1 * n1 + s1 * n0));
    } else {
        const int kvh = u - 32;
        const _Float16* base = qkv + (size_t)tok * 5120 + 4096 + kvh * 128;
        float v0 = (float)base[lane], v1 = (float)base[lane + 64];
        float ss = v0 * v0 + v1 * v1;
        #pragma unroll
        for (int m = 1; m < 64; m <<= 1) ss += __shfl_xor(ss, m);
        float rms = rsqrtf(ss * (1.f / 128.f) + 1e-6f);
        float n0 = v0 * rms * kn_w[lane], n1 = v1 * rms * kn_w[lane + 64];
        _Float16* o = kh + (((size_t)(b * 4 + kvh)) * 1024 + l) * 128;
        o[lane]      = (_Float16)(c0 * n0 - s0 * n1);
        o[lane + 64] = (_Float16)(c1 * n1 + s1 * n0);
    }
}

// ---------------------------------------------------------------- attention
// 8 waves x 32 q-rows; fixed-max exp2 softmax; dbuf K/V; l via ones-column.
__global__ __launch_bounds__(512) void k_attn(
    const _Float16* __restrict__ qh, const _Float16* __restrict__ kh,
    const _Float16* __restrict__ vth, const _Float16* __restrict__ ones16,
    _Float16* __restrict__ oh)
{
    const int bh = blockIdx.x;
    const int qb = 3 - blockIdx.y;
    const int b = bh >> 5, h = bh & 31, kv = h >> 3;
    const int tid = threadIdx.x, lane = tid & 63, wid = tid >> 6;
    const int fr = lane & 15, fg = lane >> 4;
    const int q0w = qb * 256 + wid * 32;

    __shared__ __align__(16) _Float16 Ks[2][64][128];
    __shared__ __align__(16) _Float16 Vs[2][128][64];
    __shared__ __align__(16) _Float16 Vones[16][64];
    __shared__ __align__(16) _Float16 Ps[8][32][72];

    const _Float16* kb = kh + ((size_t)(b * 4 + kv)) * 1024 * 128;
    const _Float16* vb = vth + ((size_t)(b * 4 + kv)) * 128 * 1024;

    auto stage = [&](int nb, int key0) {
        #pragma unroll
        for (int i = 0; i < 2; i++) {
            int rr = wid * 8 + i * 4 + (lane >> 4);
            int c16 = (lane & 15) ^ (rr & 15);
            load16_lds(kb + (size_t)(key0 + rr) * 128 + c16 * 8,
                       &Ks[nb][0][0] + (wid * 8 + i * 4) * 128);
        }
        #pragma unroll
        for (int i = 0; i < 2; i++) {
            int rr = wid * 16 + i * 8 + (lane >> 3);
            int c16 = (lane & 7) ^ (rr & 7);
            load16_lds(vb + (size_t)rr * 1024 + key0 + c16 * 8,
                       &Vs[nb][0][0] + (wid * 16 + i * 8) * 64);
        }
    };

    f16x8 aq[2][4];
    #pragma unroll
    for (int mi = 0; mi < 2; mi++) {
        const _Float16* qbase =
            qh + ((size_t)(b * 1024 + q0w + mi * 16 + fr)) * 4096 + h * 128;
        #pragma unroll
        for (int kk = 0; kk < 4; kk++)
            aq[mi][kk] = *reinterpret_cast<const f16x8*>(qbase + kk * 32 + fg * 8);
    }
    if (wid == 0) {
        #pragma unroll
        for (int i = 0; i < 2; i++)
            load16_lds(ones16 + (size_t)(lane + i * 64) * 8, &Vones[0][0] + i * 512);
    }
    stage(0, 0);

    const f32x4 z4 = { 0.f, 0.f, 0.f, 0.f };
    f32x4 oacc[2][9];
    #pragma unroll
    for (int mi = 0; mi < 2; mi++)
        #pragma unroll
        for (int dj = 0; dj < 9; dj++) oacc[mi][dj] = z4;

    const int ntiles = qb * 4 + 4;
    int cb = 0;
    for (int kt = 0; kt < ntiles; kt++) {
        const int key0 = kt * 64;
        asm volatile("s_waitcnt vmcnt(0)" ::: "memory");
        __builtin_amdgcn_s_barrier();
        if (kt + 1 < ntiles) stage(cb ^ 1, key0 + 64);

        if (key0 <= q0w + 31) {
            f32x4 sc[2][4];
            #pragma unroll
            for (int mi = 0; mi < 2; mi++)
                #pragma unroll
                for (int j = 0; j < 4; j++) sc[mi][j] = z4;
            __builtin_amdgcn_s_setprio(1);
            #pragma unroll
            for (int j = 0; j < 4; j++)
                #pragma unroll
                for (int kk = 0; kk < 4; kk++) {
                    f16x8 bk = *reinterpret_cast<const f16x8*>(
                        &Ks[cb][0][0] + (j * 16 + fr) * 128 + (((kk * 4 + fg) ^ fr) * 8));
                    #pragma unroll
                    for (int mi = 0; mi < 2; mi++)
                        sc[mi][j] = __builtin_amdgcn_mfma_f32_16x16x32_f16(
                            aq[mi][kk], bk, sc[mi][j], 0, 0, 0);
                }
            __builtin_amdgcn_s_setprio(0);

            const bool maskt = (key0 + 63 > q0w);
            #pragma unroll
            for (int mi = 0; mi < 2; mi++)
                #pragma unroll
                for (int j = 0; j < 4; j++) {
                    const int key = key0 + j * 16 + fr;
                    #pragma unroll
                    for (int r = 0; r < 4; r++) {
                        float v = sc[mi][j][r];
                        if (maskt && key > q0w + mi * 16 + fg * 4 + r) v = -1e30f;
                        Ps[wid][mi * 16 + fg * 4 + r][j * 16 + fr] =
                            (_Float16)__builtin_amdgcn_exp2f(v - 8.f);
                    }
                }

            __builtin_amdgcn_s_setprio(1);
            #pragma unroll
            for (int ks = 0; ks < 2; ks++) {
                f16x8 ap0 = *reinterpret_cast<const f16x8*>(
                    &Ps[wid][fr][ks * 32 + fg * 8]);
                f16x8 ap1 = *reinterpret_cast<const f16x8*>(
                    &Ps[wid][16 + fr][ks * 32 + fg * 8]);
                #pragma unroll
                for (int dj = 0; dj < 8; dj++) {
                    f16x8 bv = *reinterpret_cast<const f16x8*>(
                        &Vs[cb][0][0] + (dj * 16 + fr) * 64 + (((ks * 4 + fg) ^ (fr & 7)) * 8));
                    oacc[0][dj] = __builtin_amdgcn_mfma_f32_16x16x32_f16(ap0, bv, oacc[0][dj], 0, 0, 0);
                    oacc[1][dj] = __builtin_amdgcn_mfma_f32_16x16x32_f16(ap1, bv, oacc[1][dj], 0, 0, 0);
                }
                f16x8 bo = *reinterpret_cast<const f16x8*>(
                    &Vones[0][0] + fr * 64 + (((ks * 4 + fg) ^ (fr & 7)) * 8));
                oacc[0][8] = __builtin_amdgcn_mfma_f32_16x16x32_f16(ap0, bo, oacc[0][8], 0, 0, 0);
                oacc[1][8] = __builtin_amdgcn_mfma_f32_16x16x32_f16(ap1, bo, oacc[1][8], 0, 0, 0);
            }
            __builtin_amdgcn_s_setprio(0);
        }
        cb ^= 1;
    }

    #pragma unroll
    for (int mi = 0; mi < 2; mi++) {
        float inv[4];
        #pragma unroll
        for (int r = 0; r < 4; r++) {
            float l = __shfl(oacc[mi][8][r], lane & 48);
            inv[r] = 1.f / l;
        }
        #pragma unroll
        for (int dj = 0; dj < 8; dj++)
            #pragma unroll
            for (int r = 0; r < 4; r++)
                oh[((size_t)(b * 1024 + q0w + mi * 16 + fg * 4 + r)) * 4096
                   + h * 128 + dj * 16 + fr] = (_Float16)(oacc[mi][dj][r] * inv[r]);
    }
}

// ---------------------------------------------------------------- router (inline rmsnorm from x2)
__global__ __launch_bounds__(256) void k_router(
    const float* __restrict__ x2, const float* __restrict__ wm,
    const float* __restrict__ rw, float* __restrict__ wdense)
{
    const int tok = blockIdx.x * 4 + (threadIdx.x >> 6);
    const int lane = threadIdx.x & 63;
    __shared__ float lg[4][16];
    const float* hr = x2 + (size_t)tok * 2048;
    float vals[32];
    float ss = 0.f;
    #pragma unroll
    for (int i = 0; i < 32; i++) { float v = hr[i * 64 + lane]; vals[i] = v; ss += v * v; }
    #pragma unroll
    for (int m = 1; m < 64; m <<= 1) ss += __shfl_xor(ss, m);
    float r = rsqrtf(ss * (1.f / 2048.f) + 1e-6f);
    #pragma unroll
    for (int i = 0; i < 32; i++) vals[i] *= r * wm[i * 64 + lane];
    for (int e = 0; e < 16; e++) {
        float acc = 0.f;
        #pragma unroll
        for (int i = 0; i < 32; i++) acc += vals[i] * rw[(size_t)e * 2048 + i * 64 + lane];
        #pragma unroll
        for (int m = 1; m < 64; m <<= 1) acc += __shfl_xor(acc, m);
        if (lane == 0) lg[threadIdx.x >> 6][e] = acc;
    }
    __syncthreads();
    if (lane == 0) {
        float* l = lg[threadIdx.x >> 6];
        float mx = l[0];
        for (int e = 1; e < 16; e++) mx = fmaxf(mx, l[e]);
        float p[16]; float sum = 0.f;
        for (int e = 0; e < 16; e++) { p[e] = expf(l[e] - mx); sum += p[e]; }
        for (int e = 0; e < 16; e++) p[e] /= sum;
        bool sel[16]; for (int e = 0; e < 16; e++) sel[e] = false;
        float ssum = 0.f;
        for (int t = 0; t < 8; t++) {
            int bi = -1; float bv = -1.f;
            for (int e = 0; e < 16; e++) if (!sel[e] && p[e] > bv) { bv = p[e]; bi = e; }
            sel[bi] = true; ssum += bv;
        }
        for (int e = 0; e < 16; e++)
            wdense[(size_t)e * 4096 + tok] = sel[e] ? p[e] / ssum : 0.f;
    }
}

// ---------------------------------------------------------------- launch

extern "C" void kernel_launch(void* const* d_in, const int* in_sizes, int n_in,
                              void* d_out, int out_size, void* d_ws, size_t ws_size,
                              hipStream_t stream)
{
    const float* x        = (const float*)d_in[0];
    const float* cosb     = (const float*)d_in[1];
    const float* sinb     = (const float*)d_in[2];
    const float* nattn    = (const float*)d_in[3];
    const float* q_w      = (const float*)d_in[4];
    const float* k_w      = (const float*)d_in[5];
    const float* v_w      = (const float*)d_in[6];
    const float* qn_w     = (const float*)d_in[7];
    const float* kn_w     = (const float*)d_in[8];
    const float* o_w      = (const float*)d_in[9];
    const float* nmlp     = (const float*)d_in[10];
    const float* router_w = (const float*)d_in[11];
    const float* egw      = (const float*)d_in[12];
    const float* euw      = (const float*)d_in[13];
    const float* edw      = (const float*)d_in[14];

    char* w = (char*)d_ws;
    _Float16* qkvw_h = (_Float16*)(w + 0);          // 20.97 MB
    _Float16* ow_h   = (_Float16*)(w + 20971520);   // 16.78 MB
    _Float16* guw_h  = (_Float16*)(w + 37748736);   // 16.78 MB
    _Float16* dwc_h  = (_Float16*)(w + 54525952);   //  8.39 MB
    _Float16* h_h    = (_Float16*)(w + 62914560);   // 16.78 MB (aliased hm_h)
    _Float16* hm_h   = h_h;
    float*    x2     = (float*)(w + 79691776);      // 33.55 MB
    _Float16* qkv_h  = (_Float16*)(w + 113246208);  // 41.94 MB (alias o_h, ab_h)
    _Float16* o_h    = qkv_h;
    _Float16* ab_h   = qkv_h;
    _Float16* q_h    = (_Float16*)(w + 155189248);  // 33.55 MB
    _Float16* k_h    = (_Float16*)(w + 188743680);  //  4.19 MB
    _Float16* vt_h   = (_Float16*)(w + 192937984);  //  4.19 MB
    float*    wdense = (float*)(w + 197132288);     //  0.26 MB
    _Float16* ones_h = (_Float16*)(w + 197394432);  //  2 KB (16x64 f16)

    k_castall<<<26625, 256, 0, stream>>>(q_w, k_w, v_w, o_w, egw, euw, edw,
                                         qkvw_h, ow_h, guw_h, dwc_h, ones_h);
    k_rmsnorm<<<4096, 256, 0, stream>>>(x, nattn, h_h);
    k_gemm8<<<dim3(16, 16), 512, 0, stream>>>(h_h, 2048, qkvw_h, 2048, qkv_h, 5120, 2048,
                                              nullptr, nullptr);
    k_gemm<<<dim3(32, 8), 256, 0, stream>>>(h_h, 2048, qkvw_h + (size_t)4096 * 2048, 2048,
                                            nullptr, qkv_h + 4096, 5120, nullptr, 2048);
    k_qkv_post<<<dim3(4096, 10), 256, 0, stream>>>(qkv_h, cosb, sinb, qn_w, kn_w,
                                                   q_h, k_h, vt_h);
    k_attn<<<dim3(128, 4), 512, 0, stream>>>(q_h, k_h, vt_h, ones_h, o_h);
    k_gemm<<<dim3(32, 16), 256, 0, stream>>>(o_h, 4096, ow_h, 4096,
                                             x2, nullptr, 2048, x, 4096);
    k_rmsnorm<<<4096, 256, 0, stream>>>(x2, nmlp, hm_h);
    k_router<<<1024, 256, 0, stream>>>(x2, nmlp, router_w, wdense);
    k_gemm8<<<dim3(16, 16), 512, 0, stream>>>(hm_h, 2048, guw_h, 2048, nullptr, 0, 2048,
                                              wdense, ab_h);
    k_gemm<<<dim3(32, 16), 256, 0, stream>>>(ab_h, 2048, dwc_h, 2048,
                                             (float*)d_out, nullptr, 2048, x2, 2048);

    (void)in_sizes; (void)n_in; (void)out_size; (void)ws_size;
}

// Round 16
// 481.601 us; speedup vs baseline: 1.0036x; 1.0036x over previous
//
#include <hip/hip_runtime.h>
#include <stdint.h>

typedef _Float16 f16x8 __attribute__((ext_vector_type(8)));
typedef _Float16 f16x4 __attribute__((ext_vector_type(4)));
typedef float    f32x4 __attribute__((ext_vector_type(4)));

__device__ __forceinline__ void load16_lds(const _Float16* g, _Float16* l) {
    __builtin_amdgcn_global_load_lds(
        (const __attribute__((address_space(1))) void*)g,
        (__attribute__((address_space(3))) void*)l, 16, 0, 0);
}

// ---------------------------------------------------------------- fused casts + attn rmsnorm
// [0,18432): q/k/v/o cast; [18432,22528): guw; [22528,26624): dwc; 26624: ones;
// [26625,30721): rmsnorm(x) -> h (f16).
__global__ __launch_bounds__(256) void k_castall(
    const float* __restrict__ q, const float* __restrict__ k,
    const float* __restrict__ v, const float* __restrict__ o,
    const float* __restrict__ eg, const float* __restrict__ eu,
    const float* __restrict__ edw,
    const float* __restrict__ x, const float* __restrict__ nattn,
    _Float16* __restrict__ qkvw, _Float16* __restrict__ ow,
    _Float16* __restrict__ guw, _Float16* __restrict__ dwc,
    _Float16* __restrict__ ones16, _Float16* __restrict__ h)
{
    const int bid = blockIdx.x;
    if (bid < 18432) {
        size_t i = ((size_t)bid * 256 + threadIdx.x) * 4;
        const float* src; _Float16* dst;
        if (i < 8388608)        { src = q + i;             dst = qkvw + i; }
        else if (i < 9437184)   { src = k + (i - 8388608); dst = qkvw + i; }
        else if (i < 10485760)  { src = v + (i - 9437184); dst = qkvw + i; }
        else                    { src = o + (i - 10485760); dst = ow + (i - 10485760); }
        float4 xx = *reinterpret_cast<const float4*>(src);
        f16x4 y = { (_Float16)xx.x, (_Float16)xx.y, (_Float16)xx.z, (_Float16)xx.w };
        *reinterpret_cast<f16x4*>(dst) = y;
    } else if (bid < 22528) {
        const int row = bid - 18432;
        const int e = row >> 8, rem = row & 255, half = rem >> 7, mi = rem & 127;
        const float* src = (half ? eu : eg) + ((size_t)(e * 128 + mi)) * 2048;
        const int c = threadIdx.x * 8;
        float4 v0 = *reinterpret_cast<const float4*>(src + c);
        float4 v1 = *reinterpret_cast<const float4*>(src + c + 4);
        f16x8 ov = { (_Float16)v0.x,(_Float16)v0.y,(_Float16)v0.z,(_Float16)v0.w,
                     (_Float16)v1.x,(_Float16)v1.y,(_Float16)v1.z,(_Float16)v1.w };
        *reinterpret_cast<f16x8*>(guw + (size_t)row * 2048 + c) = ov;
    } else if (bid < 26624) {
        int t = (bid - 22528) * 256 + threadIdx.x;
        int mi4 = (t & 31) * 4;
        int dm = (t >> 5) & 2047;
        int e = t >> 16;
        float4 vv = *reinterpret_cast<const float4*>(edw + (((size_t)e * 2048 + dm) << 7) + mi4);
        f16x4 ov = { (_Float16)vv.x, (_Float16)vv.y, (_Float16)vv.z, (_Float16)vv.w };
        *reinterpret_cast<f16x4*>(dwc + ((size_t)dm << 11) + e * 128 + mi4) = ov;
    } else if (bid == 26624) {
        int i = threadIdx.x;
        _Float16 vv = (i < 16) ? (_Float16)1.0f : (_Float16)0.0f;
        f16x4 ov = { vv, vv, vv, vv };
        *reinterpret_cast<f16x4*>(ones16 + i * 4) = ov;
    } else {
        const int row = bid - 26625, tid = threadIdx.x;
        const float* xr = x + (size_t)row * 2048;
        float4 a = *reinterpret_cast<const float4*>(xr + tid * 8);
        float4 b = *reinterpret_cast<const float4*>(xr + tid * 8 + 4);
        float ss = a.x*a.x + a.y*a.y + a.z*a.z + a.w*a.w
                 + b.x*b.x + b.y*b.y + b.z*b.z + b.w*b.w;
        #pragma unroll
        for (int m = 1; m < 64; m <<= 1) ss += __shfl_xor(ss, m);
        __shared__ float red[4];
        if ((tid & 63) == 0) red[tid >> 6] = ss;
        __syncthreads();
        float tot = red[0] + red[1] + red[2] + red[3];
        float r = rsqrtf(tot * (1.f / 2048.f) + 1e-6f);
        float4 wa = *reinterpret_cast<const float4*>(nattn + tid * 8);
        float4 wb = *reinterpret_cast<const float4*>(nattn + tid * 8 + 4);
        f16x8 hv = { (_Float16)(a.x*r*wa.x), (_Float16)(a.y*r*wa.y),
                     (_Float16)(a.z*r*wa.z), (_Float16)(a.w*r*wa.w),
                     (_Float16)(b.x*r*wb.x), (_Float16)(b.y*r*wb.y),
                     (_Float16)(b.z*r*wb.z), (_Float16)(b.w*r*wb.w) };
        *reinterpret_cast<f16x8*>(h + (size_t)row * 2048 + tid * 8) = hv;
    }
}

// ---------------------------------------------------------------- GEMM 128x128
__global__ __launch_bounds__(256) void k_gemm(
    const _Float16* __restrict__ A, int lda,
    const _Float16* __restrict__ W, int ldw,
    float* __restrict__ Cf, _Float16* __restrict__ Ch, int ldc,
    const float* __restrict__ resid, int K)
{
    __shared__ __align__(16) _Float16 As[3][128][32];
    __shared__ __align__(16) _Float16 Ws[3][128][32];
    const int r0 = blockIdx.x * 128, c0 = blockIdx.y * 128;
    const int tid = threadIdx.x, lane = tid & 63, wid = tid >> 6;
    const int wr = wid >> 1, wc = wid & 1;
    const int sr = lane >> 2;
    const int scs = ((lane & 3) ^ ((lane >> 3) & 3)) * 8;
    const int fr = lane & 15;
    const int rks = (((lane >> 4) ^ ((fr >> 1) & 3))) * 8;
    const f32x4 z4 = { 0.f, 0.f, 0.f, 0.f };
    f32x4 acc[4][4];
    #pragma unroll
    for (int i = 0; i < 4; i++)
        #pragma unroll
        for (int j = 0; j < 4; j++) acc[i][j] = z4;

    auto stage = [&](int bf, int k0) {
        #pragma unroll
        for (int i = 0; i < 2; i++) {
            int ch = wid * 2 + i;
            load16_lds(A + (size_t)(r0 + ch * 16 + sr) * lda + k0 + scs, &As[bf][ch * 16][0]);
            load16_lds(W + (size_t)(c0 + ch * 16 + sr) * ldw + k0 + scs, &Ws[bf][ch * 16][0]);
        }
    };

    const int nt = K >> 5;
    stage(0, 0);
    if (nt > 1) stage(1, 32);
    int cur = 0;
    for (int t = 0; t < nt; t++) {
        if (t < nt - 1) asm volatile("s_waitcnt vmcnt(4)" ::: "memory");
        else            asm volatile("s_waitcnt vmcnt(0)" ::: "memory");
        __builtin_amdgcn_s_barrier();
        f16x8 af[4], bf4[4];
        #pragma unroll
        for (int i = 0; i < 4; i++)
            af[i] = *reinterpret_cast<const f16x8*>(&As[cur][wr * 64 + i * 16 + fr][rks]);
        #pragma unroll
        for (int j = 0; j < 4; j++)
            bf4[j] = *reinterpret_cast<const f16x8*>(&Ws[cur][wc * 64 + j * 16 + fr][rks]);
        if (t + 2 < nt) stage((t + 2) % 3, (t + 2) << 5);
        __builtin_amdgcn_s_setprio(1);
        #pragma unroll
        for (int i = 0; i < 4; i++)
            #pragma unroll
            for (int j = 0; j < 4; j++)
                acc[i][j] = __builtin_amdgcn_mfma_f32_16x16x32_f16(af[i], bf4[j], acc[i][j], 0, 0, 0);
        __builtin_amdgcn_s_setprio(0);
        cur = (cur + 1) % 3;
    }
    #pragma unroll
    for (int i = 0; i < 4; i++) {
        const int rowb = r0 + wr * 64 + i * 16 + (lane >> 4) * 4;
        #pragma unroll
        for (int j = 0; j < 4; j++) {
            const int col = c0 + wc * 64 + j * 16 + fr;
            #pragma unroll
            for (int r = 0; r < 4; r++) {
                size_t idx = (size_t)(rowb + r) * ldc + col;
                float v = acc[i][j][r];
                if (resid) v += resid[idx];
                if (Ch) Ch[idx] = (_Float16)v;
                else    Cf[idx] = v;
            }
        }
    }
}

// ---------------------------------------------------------------- GEMM 256x256, 8 waves
// gu-mode (wdense!=null): fused silu(g)*u*w_e epilogue -> ab.
__global__ __launch_bounds__(512, 2) void k_gemm8(
    const _Float16* __restrict__ A, int lda,
    const _Float16* __restrict__ W, int ldw,
    _Float16* __restrict__ Ch, int ldc, int K,
    const float* __restrict__ wdense, _Float16* __restrict__ ab)
{
    __shared__ __align__(16) _Float16 As[3][256][32];
    __shared__ __align__(16) _Float16 Ws[3][256][32];
    const int r0 = blockIdx.x * 256, c0 = blockIdx.y * 256;
    const int tid = threadIdx.x, lane = tid & 63, wid = tid >> 6;
    const int wr = wid >> 2, wc = wid & 3;
    const int rA = lane >> 2;
    const int scs = ((lane & 3) ^ ((lane >> 3) & 3)) * 8;
    const int fr = lane & 15, fg = lane >> 4;
    const int rks = (((lane >> 4) ^ ((fr >> 1) & 3))) * 8;
    const f32x4 z4 = { 0.f, 0.f, 0.f, 0.f };
    f32x4 acc[8][4];
    #pragma unroll
    for (int i = 0; i < 8; i++)
        #pragma unroll
        for (int j = 0; j < 4; j++) acc[i][j] = z4;

    auto stage = [&](int bf, int k0) {
        #pragma unroll
        for (int i = 0; i < 2; i++) {
            load16_lds(A + (size_t)(r0 + i * 128 + wid * 16 + rA) * lda + k0 + scs,
                       &As[bf][i * 128 + wid * 16][0]);
            load16_lds(W + (size_t)(c0 + i * 128 + wid * 16 + rA) * ldw + k0 + scs,
                       &Ws[bf][i * 128 + wid * 16][0]);
        }
    };

    const int nt = K >> 5;
    stage(0, 0);
    if (nt > 1) stage(1, 32);
    int cur = 0;
    for (int t = 0; t < nt; t++) {
        if (t < nt - 1) asm volatile("s_waitcnt vmcnt(4)" ::: "memory");
        else            asm volatile("s_waitcnt vmcnt(0)" ::: "memory");
        __builtin_amdgcn_s_barrier();
        f16x8 af[8], bf4[4];
        #pragma unroll
        for (int i = 0; i < 8; i++)
            af[i] = *reinterpret_cast<const f16x8*>(&As[cur][wr * 128 + i * 16 + fr][rks]);
        #pragma unroll
        for (int j = 0; j < 4; j++)
            bf4[j] = *reinterpret_cast<const f16x8*>(&Ws[cur][wc * 64 + j * 16 + fr][rks]);
        if (t + 2 < nt) stage((t + 2) % 3, (t + 2) << 5);
        __builtin_amdgcn_s_setprio(1);
        #pragma unroll
        for (int i = 0; i < 8; i++)
            #pragma unroll
            for (int j = 0; j < 4; j++)
                acc[i][j] = __builtin_amdgcn_mfma_f32_16x16x32_f16(af[i], bf4[j], acc[i][j], 0, 0, 0);
        __builtin_amdgcn_s_setprio(0);
        cur = (cur + 1) % 3;
    }

    if (!wdense) {
        #pragma unroll
        for (int i = 0; i < 8; i++) {
            const int rowb = r0 + wr * 128 + i * 16 + fg * 4;
            #pragma unroll
            for (int j = 0; j < 4; j++) {
                const int col = c0 + wc * 64 + j * 16 + fr;
                #pragma unroll
                for (int r = 0; r < 4; r++)
                    Ch[(size_t)(rowb + r) * ldc + col] = (_Float16)acc[i][j][r];
            }
        }
        return;
    }

    _Float16* LgA = &As[0][0][0];
    _Float16* LgB = &Ws[0][0][0];
    auto lgp = [&](int row, int mi) -> _Float16* {
        return ((row < 128) ? LgA : LgB) + (size_t)(row & 127) * 136 + mi;
    };
    const int e = blockIdx.y;
    __syncthreads();
    if (wc < 2) {
        #pragma unroll
        for (int i = 0; i < 8; i++) {
            const int row = wr * 128 + i * 16 + fg * 4;
            #pragma unroll
            for (int j = 0; j < 4; j++) {
                const int mi = wc * 64 + j * 16 + fr;
                #pragma unroll
                for (int r = 0; r < 4; r++)
                    *lgp(row + r, mi) = (_Float16)acc[i][j][r];
            }
        }
    }
    __syncthreads();
    if (wc >= 2) {
        #pragma unroll
        for (int i = 0; i < 8; i++) {
            const int row = wr * 128 + i * 16 + fg * 4;
            #pragma unroll
            for (int j = 0; j < 4; j++) {
                const int mi = (wc - 2) * 64 + j * 16 + fr;
                #pragma unroll
                for (int r = 0; r < 4; r++) {
                    float g = (float)*lgp(row + r, mi);
                    float sil = g / (1.f + __expf(-g));
                    *lgp(row + r, mi) = (_Float16)(sil * acc[i][j][r]);
                }
            }
        }
    }
    __syncthreads();
    #pragma unroll
    for (int pass = 0; pass < 8; pass++) {
        int cid = pass * 512 + tid;
        int row = cid >> 4, col8 = cid & 15;
        f16x8 v = *reinterpret_cast<const f16x8*>(
            ((row < 128) ? LgA : LgB) + (size_t)(row & 127) * 136 + col8 * 8);
        float wv = wdense[(size_t)e * 4096 + r0 + row];
        f16x8 o;
        #pragma unroll
        for (int j = 0; j < 8; j++) o[j] = (_Float16)((float)v[j] * wv);
        *reinterpret_cast<f16x8*>(ab + (size_t)(r0 + row) * 2048 + e * 128 + col8 * 8) = o;
    }
}

// ------------------------------------------- per-head RMSNorm + RoPE + V-transpose
__global__ __launch_bounds__(256) void k_qkv_post(
    const _Float16* __restrict__ qkv,
    const float* __restrict__ cosb, const float* __restrict__ sinb,
    const float* __restrict__ qn_w, const float* __restrict__ kn_w,
    _Float16* __restrict__ qh, _Float16* __restrict__ kh,
    _Float16* __restrict__ vth)
{
    if (blockIdx.y == 9) {
        const int unit = blockIdx.x;
        if (unit >= 512) return;
        const int bkv = unit >> 5, rem = unit & 31;
        const int l0 = (rem >> 1) * 64, d0 = (rem & 1) * 64;
        const int b = bkv >> 2, kv = bkv & 3;
        __shared__ _Float16 T[64][72];
        const int t = threadIdx.x;
        const int r = t >> 3, c8 = (t & 7) * 8;
        #pragma unroll
        for (int rr = 0; rr < 2; rr++) {
            int l = l0 + r + rr * 32;
            *reinterpret_cast<f16x8*>(&T[r + rr * 32][c8]) =
                *reinterpret_cast<const f16x8*>(
                    qkv + (size_t)(b * 1024 + l) * 5120 + 4608 + kv * 128 + d0 + c8);
        }
        __syncthreads();
        #pragma unroll
        for (int rr = 0; rr < 2; rr++) {
            int d = d0 + r + rr * 32;
            f16x8 v;
            #pragma unroll
            for (int j = 0; j < 8; j++) v[j] = T[c8 + j][r + rr * 32];
            *reinterpret_cast<f16x8*>(vth + ((size_t)(bkv * 128 + d)) * 1024 + l0 + c8) = v;
        }
        return;
    }
    const int tok = blockIdx.x;
    const int u = blockIdx.y * 4 + (threadIdx.x >> 6);
    const int lane = threadIdx.x & 63;
    const int b = tok >> 10, l = tok & 1023;
    const float SCL = 0.12752887074166638f;   // 1/sqrt(128) * log2(e)
    const float c0 = cosb[(size_t)tok * 128 + lane];
    const float c1 = cosb[(size_t)tok * 128 + lane + 64];
    const float s0 = sinb[(size_t)tok * 128 + lane];
    const float s1 = sinb[(size_t)tok * 128 + lane + 64];
    if (u < 32) {
        const _Float16* base = qkv + (size_t)tok * 5120 + u * 128;
        float v0 = (float)base[lane], v1 = (float)base[lane + 64];
        float ss = v0 * v0 + v1 * v1;
        #pragma unroll
        for (int m = 1; m < 64; m <<= 1) ss += __shfl_xor(ss, m);
        float rms = rsqrtf(ss * (1.f / 128.f) + 1e-6f);
        float n0 = v0 * rms * qn_w[lane], n1 = v1 * rms * qn_w[lane + 64];
        _Float16* o = qh + (size_t)tok * 4096 + u * 128;
        o[lane]      = (_Float16)(SCL * (c0 * n0 - s0 * n1));
        o[lane + 64] = (_Float16)(SCL * (c1 * n1 + s1 * n0));
    } else {
        const int kvh = u - 32;
        const _Float16* base = qkv + (size_t)tok * 5120 + 4096 + kvh * 128;
        float v0 = (float)base[lane], v1 = (float)base[lane + 64];
        float ss = v0 * v0 + v1 * v1;
        #pragma unroll
        for (int m = 1; m < 64; m <<= 1) ss += __shfl_xor(ss, m);
        float rms = rsqrtf(ss * (1.f / 128.f) + 1e-6f);
        float n0 = v0 * rms * kn_w[lane], n1 = v1 * rms * kn_w[lane + 64];
        _Float16* o = kh + (((size_t)(b * 4 + kvh)) * 1024 + l) * 128;
        o[lane]      = (_Float16)(c0 * n0 - s0 * n1);
        o[lane + 64] = (_Float16)(c1 * n1 + s1 * n0);
    }
}

// ---------------------------------------------------------------- attention
__global__ __launch_bounds__(512) void k_attn(
    const _Float16* __restrict__ qh, const _Float16* __restrict__ kh,
    const _Float16* __restrict__ vth, const _Float16* __restrict__ ones16,
    _Float16* __restrict__ oh)
{
    const int bh = blockIdx.x;
    const int qb = 3 - blockIdx.y;
    const int b = bh >> 5, h = bh & 31, kv = h >> 3;
    const int tid = threadIdx.x, lane = tid & 63, wid = tid >> 6;
    const int fr = lane & 15, fg = lane >> 4;
    const int q0w = qb * 256 + wid * 32;

    __shared__ __align__(16) _Float16 Ks[2][64][128];
    __shared__ __align__(16) _Float16 Vs[2][128][64];
    __shared__ __align__(16) _Float16 Vones[16][64];
    __shared__ __align__(16) _Float16 Ps[8][32][72];

    const _Float16* kb = kh + ((size_t)(b * 4 + kv)) * 1024 * 128;
    const _Float16* vb = vth + ((size_t)(b * 4 + kv)) * 128 * 1024;

    auto stage = [&](int nb, int key0) {
        #pragma unroll
        for (int i = 0; i < 2; i++) {
            int rr = wid * 8 + i * 4 + (lane >> 4);
            int c16 = (lane & 15) ^ (rr & 15);
            load16_lds(kb + (size_t)(key0 + rr) * 128 + c16 * 8,
                       &Ks[nb][0][0] + (wid * 8 + i * 4) * 128);
        }
        #pragma unroll
        for (int i = 0; i < 2; i++) {
            int rr = wid * 16 + i * 8 + (lane >> 3);
            int c16 = (lane & 7) ^ (rr & 7);
            load16_lds(vb + (size_t)rr * 1024 + key0 + c16 * 8,
                       &Vs[nb][0][0] + (wid * 16 + i * 8) * 64);
        }
    };

    f16x8 aq[2][4];
    #pragma unroll
    for (int mi = 0; mi < 2; mi++) {
        const _Float16* qbase =
            qh + ((size_t)(b * 1024 + q0w + mi * 16 + fr)) * 4096 + h * 128;
        #pragma unroll
        for (int kk = 0; kk < 4; kk++)
            aq[mi][kk] = *reinterpret_cast<const f16x8*>(qbase + kk * 32 + fg * 8);
    }
    if (wid == 0) {
        #pragma unroll
        for (int i = 0; i < 2; i++)
            load16_lds(ones16 + (size_t)(lane + i * 64) * 8, &Vones[0][0] + i * 512);
    }
    stage(0, 0);

    const f32x4 z4 = { 0.f, 0.f, 0.f, 0.f };
    f32x4 oacc[2][9];
    #pragma unroll
    for (int mi = 0; mi < 2; mi++)
        #pragma unroll
        for (int dj = 0; dj < 9; dj++) oacc[mi][dj] = z4;

    const int ntiles = qb * 4 + 4;
    int cb = 0;
    for (int kt = 0; kt < ntiles; kt++) {
        const int key0 = kt * 64;
        asm volatile("s_waitcnt vmcnt(0)" ::: "memory");
        __builtin_amdgcn_s_barrier();
        if (kt + 1 < ntiles) stage(cb ^ 1, key0 + 64);

        if (key0 <= q0w + 31) {
            f32x4 sc[2][4];
            #pragma unroll
            for (int mi = 0; mi < 2; mi++)
                #pragma unroll
                for (int j = 0; j < 4; j++) sc[mi][j] = z4;
            __builtin_amdgcn_s_setprio(1);
            #pragma unroll
            for (int j = 0; j < 4; j++)
                #pragma unroll
                for (int kk = 0; kk < 4; kk++) {
                    f16x8 bk = *reinterpret_cast<const f16x8*>(
                        &Ks[cb][0][0] + (j * 16 + fr) * 128 + (((kk * 4 + fg) ^ fr) * 8));
                    #pragma unroll
                    for (int mi = 0; mi < 2; mi++)
                        sc[mi][j] = __builtin_amdgcn_mfma_f32_16x16x32_f16(
                            aq[mi][kk], bk, sc[mi][j], 0, 0, 0);
                }
            __builtin_amdgcn_s_setprio(0);

            const bool maskt = (key0 + 63 > q0w);
            #pragma unroll
            for (int mi = 0; mi < 2; mi++)
                #pragma unroll
                for (int j = 0; j < 4; j++) {
                    const int key = key0 + j * 16 + fr;
                    #pragma unroll
                    for (int r = 0; r < 4; r++) {
                        float v = sc[mi][j][r];
                        if (maskt && key > q0w + mi * 16 + fg * 4 + r) v = -1e30f;
                        Ps[wid][mi * 16 + fg * 4 + r][j * 16 + fr] =
                            (_Float16)__builtin_amdgcn_exp2f(v - 8.f);
                    }
                }

            __builtin_amdgcn_s_setprio(1);
            #pragma unroll
            for (int ks = 0; ks < 2; ks++) {
                f16x8 ap0 = *reinterpret_cast<const f16x8*>(
                    &Ps[wid][fr][ks * 32 + fg * 8]);
                f16x8 ap1 = *reinterpret_cast<const f16x8*>(
                    &Ps[wid][16 + fr][ks * 32 + fg * 8]);
                #pragma unroll
                for (int dj = 0; dj < 8; dj++) {
                    f16x8 bv = *reinterpret_cast<const f16x8*>(
                        &Vs[cb][0][0] + (dj * 16 + fr) * 64 + (((ks * 4 + fg) ^ (fr & 7)) * 8));
                    oacc[0][dj] = __builtin_amdgcn_mfma_f32_16x16x32_f16(ap0, bv, oacc[0][dj], 0, 0, 0);
                    oacc[1][dj] = __builtin_amdgcn_mfma_f32_16x16x32_f16(ap1, bv, oacc[1][dj], 0, 0, 0);
                }
                f16x8 bo = *reinterpret_cast<const f16x8*>(
                    &Vones[0][0] + fr * 64 + (((ks * 4 + fg) ^ (fr & 7)) * 8));
                oacc[0][8] = __builtin_amdgcn_mfma_f32_16x16x32_f16(ap0, bo, oacc[0][8], 0, 0, 0);
                oacc[1][8] = __builtin_amdgcn_mfma_f32_16x16x32_f16(ap1, bo, oacc[1][8], 0, 0, 0);
            }
            __builtin_amdgcn_s_setprio(0);
        }
        cb ^= 1;
    }

    #pragma unroll
    for (int mi = 0; mi < 2; mi++) {
        float inv[4];
        #pragma unroll
        for (int r = 0; r < 4; r++) {
            float l = __shfl(oacc[mi][8][r], lane & 48);
            inv[r] = 1.f / l;
        }
        #pragma unroll
        for (int dj = 0; dj < 8; dj++)
            #pragma unroll
            for (int r = 0; r < 4; r++)
                oh[((size_t)(b * 1024 + q0w + mi * 16 + fg * 4 + r)) * 4096
                   + h * 128 + dj * 16 + fr] = (_Float16)(oacc[mi][dj][r] * inv[r]);
    }
}

// ---------------------------------------------------------------- mlp pre: rmsnorm + router
// blocks [0,4096): rmsnorm(x2)->hm f16; [4096,5120): router (4 toks/block).
__global__ __launch_bounds__(256) void k_mlppre(
    const float* __restrict__ x2, const float* __restrict__ nmlp,
    const float* __restrict__ rw,
    _Float16* __restrict__ hm, float* __restrict__ wdense)
{
    const int bid = blockIdx.x;
    if (bid < 4096) {
        const int row = bid, tid = threadIdx.x;
        const float* xr = x2 + (size_t)row * 2048;
        float4 a = *reinterpret_cast<const float4*>(xr + tid * 8);
        float4 b = *reinterpret_cast<const float4*>(xr + tid * 8 + 4);
        float ss = a.x*a.x + a.y*a.y + a.z*a.z + a.w*a.w
                 + b.x*b.x + b.y*b.y + b.z*b.z + b.w*b.w;
        #pragma unroll
        for (int m = 1; m < 64; m <<= 1) ss += __shfl_xor(ss, m);
        __shared__ float red[4];
        if ((tid & 63) == 0) red[tid >> 6] = ss;
        __syncthreads();
        float tot = red[0] + red[1] + red[2] + red[3];
        float r = rsqrtf(tot * (1.f / 2048.f) + 1e-6f);
        float4 wa = *reinterpret_cast<const float4*>(nmlp + tid * 8);
        float4 wb = *reinterpret_cast<const float4*>(nmlp + tid * 8 + 4);
        f16x8 hv = { (_Float16)(a.x*r*wa.x), (_Float16)(a.y*r*wa.y),
                     (_Float16)(a.z*r*wa.z), (_Float16)(a.w*r*wa.w),
                     (_Float16)(b.x*r*wb.x), (_Float16)(b.y*r*wb.y),
                     (_Float16)(b.z*r*wb.z), (_Float16)(b.w*r*wb.w) };
        *reinterpret_cast<f16x8*>(hm + (size_t)row * 2048 + tid * 8) = hv;
        return;
    }
    const int tok = (bid - 4096) * 4 + (threadIdx.x >> 6);
    const int lane = threadIdx.x & 63;
    __shared__ float lg[4][16];
    const float* hr = x2 + (size_t)tok * 2048;
    float vals[32];
    float ss = 0.f;
    #pragma unroll
    for (int i = 0; i < 32; i++) { float v = hr[i * 64 + lane]; vals[i] = v; ss += v * v; }
    #pragma unroll
    for (int m = 1; m < 64; m <<= 1) ss += __shfl_xor(ss, m);
    float r = rsqrtf(ss * (1.f / 2048.f) + 1e-6f);
    #pragma unroll
    for (int i = 0; i < 32; i++) vals[i] *= r * nmlp[i * 64 + lane];
    for (int e = 0; e < 16; e++) {
        float acc = 0.f;
        #pragma unroll
        for (int i = 0; i < 32; i++) acc += vals[i] * rw[(size_t)e * 2048 + i * 64 + lane];
        #pragma unroll
        for (int m = 1; m < 64; m <<= 1) acc += __shfl_xor(acc, m);
        if (lane == 0) lg[threadIdx.x >> 6][e] = acc;
    }
    __syncthreads();
    if (lane == 0) {
        float* l = lg[threadIdx.x >> 6];
        float mx = l[0];
        for (int e = 1; e < 16; e++) mx = fmaxf(mx, l[e]);
        float p[16]; float sum = 0.f;
        for (int e = 0; e < 16; e++) { p[e] = expf(l[e] - mx); sum += p[e]; }
        for (int e = 0; e < 16; e++) p[e] /= sum;
        bool sel[16]; for (int e = 0; e < 16; e++) sel[e] = false;
        float ssum = 0.f;
        for (int t = 0; t < 8; t++) {
            int bi = -1; float bv = -1.f;
            for (int e = 0; e < 16; e++) if (!sel[e] && p[e] > bv) { bv = p[e]; bi = e; }
            sel[bi] = true; ssum += bv;
        }
        for (int e = 0; e < 16; e++)
            wdense[(size_t)e * 4096 + tok] = sel[e] ? p[e] / ssum : 0.f;
    }
}

// ---------------------------------------------------------------- launch

extern "C" void kernel_launch(void* const* d_in, const int* in_sizes, int n_in,
                              void* d_out, int out_size, void* d_ws, size_t ws_size,
                              hipStream_t stream)
{
    const float* x        = (const float*)d_in[0];
    const float* cosb     = (const float*)d_in[1];
    const float* sinb     = (const float*)d_in[2];
    const float* nattn    = (const float*)d_in[3];
    const float* q_w      = (const float*)d_in[4];
    const float* k_w      = (const float*)d_in[5];
    const float* v_w      = (const float*)d_in[6];
    const float* qn_w     = (const float*)d_in[7];
    const float* kn_w     = (const float*)d_in[8];
    const float* o_w      = (const float*)d_in[9];
    const float* nmlp     = (const float*)d_in[10];
    const float* router_w = (const float*)d_in[11];
    const float* egw      = (const float*)d_in[12];
    const float* euw      = (const float*)d_in[13];
    const float* edw      = (const float*)d_in[14];

    char* w = (char*)d_ws;
    _Float16* qkvw_h = (_Float16*)(w + 0);          // 20.97 MB
    _Float16* ow_h   = (_Float16*)(w + 20971520);   // 16.78 MB
    _Float16* guw_h  = (_Float16*)(w + 37748736);   // 16.78 MB
    _Float16* dwc_h  = (_Float16*)(w + 54525952);   //  8.39 MB
    _Float16* h_h    = (_Float16*)(w + 62914560);   // 16.78 MB (aliased hm_h)
    _Float16* hm_h   = h_h;
    float*    x2     = (float*)(w + 79691776);      // 33.55 MB
    _Float16* qkv_h  = (_Float16*)(w + 113246208);  // 41.94 MB (alias o_h, ab_h)
    _Float16* o_h    = qkv_h;
    _Float16* ab_h   = qkv_h;
    _Float16* q_h    = (_Float16*)(w + 155189248);  // 33.55 MB
    _Float16* k_h    = (_Float16*)(w + 188743680);  //  4.19 MB
    _Float16* vt_h   = (_Float16*)(w + 192937984);  //  4.19 MB
    float*    wdense = (float*)(w + 197132288);     //  0.26 MB
    _Float16* ones_h = (_Float16*)(w + 197394432);  //  2 KB (16x64 f16)

    k_castall<<<30721, 256, 0, stream>>>(q_w, k_w, v_w, o_w, egw, euw, edw, x, nattn,
                                         qkvw_h, ow_h, guw_h, dwc_h, ones_h, h_h);
    k_gemm8<<<dim3(16, 16), 512, 0, stream>>>(h_h, 2048, qkvw_h, 2048, qkv_h, 5120, 2048,
                                              nullptr, nullptr);
    k_gemm<<<dim3(32, 8), 256, 0, stream>>>(h_h, 2048, qkvw_h + (size_t)4096 * 2048, 2048,
                                            nullptr, qkv_h + 4096, 5120, nullptr, 2048);
    k_qkv_post<<<dim3(4096, 10), 256, 0, stream>>>(qkv_h, cosb, sinb, qn_w, kn_w,
                                                   q_h, k_h, vt_h);
    k_attn<<<dim3(128, 4), 512, 0, stream>>>(q_h, k_h, vt_h, ones_h, o_h);
    k_gemm<<<dim3(32, 16), 256, 0, stream>>>(o_h, 4096, ow_h, 4096,
                                             x2, nullptr, 2048, x, 4096);
    k_mlppre<<<5120, 256, 0, stream>>>(x2, nmlp, router_w, hm_h, wdense);
    k_gemm8<<<dim3(16, 16), 512, 0, stream>>>(hm_h, 2048, guw_h, 2048, nullptr, 0, 2048,
                                              wdense, ab_h);
    k_gemm<<<dim3(32, 16), 256, 0, stream>>>(ab_h, 2048, dwc_h, 2048,
                                             (float*)d_out, nullptr, 2048, x2, 2048);

    (void)in_sizes; (void)n_in; (void)out_size; (void)ws_size;
}

// Round 17
// 480.537 us; speedup vs baseline: 1.0058x; 1.0022x over previous
//
#include <hip/hip_runtime.h>
#include <stdint.h>

typedef _Float16 f16x8 __attribute__((ext_vector_type(8)));
typedef _Float16 f16x4 __attribute__((ext_vector_type(4)));
typedef float    f32x4 __attribute__((ext_vector_type(4)));

__device__ __forceinline__ void load16_lds(const _Float16* g, _Float16* l) {
    __builtin_amdgcn_global_load_lds(
        (const __attribute__((address_space(1))) void*)g,
        (__attribute__((address_space(3))) void*)l, 16, 0, 0);
}

// ---------------------------------------------------------------- fused casts + attn rmsnorm
__global__ __launch_bounds__(256) void k_castall(
    const float* __restrict__ q, const float* __restrict__ k,
    const float* __restrict__ v, const float* __restrict__ o,
    const float* __restrict__ eg, const float* __restrict__ eu,
    const float* __restrict__ edw,
    const float* __restrict__ x, const float* __restrict__ nattn,
    _Float16* __restrict__ qkvw, _Float16* __restrict__ ow,
    _Float16* __restrict__ guw, _Float16* __restrict__ dwc,
    _Float16* __restrict__ ones16, _Float16* __restrict__ h)
{
    const int bid = blockIdx.x;
    if (bid < 18432) {
        size_t i = ((size_t)bid * 256 + threadIdx.x) * 4;
        const float* src; _Float16* dst;
        if (i < 8388608)        { src = q + i;             dst = qkvw + i; }
        else if (i < 9437184)   { src = k + (i - 8388608); dst = qkvw + i; }
        else if (i < 10485760)  { src = v + (i - 9437184); dst = qkvw + i; }
        else                    { src = o + (i - 10485760); dst = ow + (i - 10485760); }
        float4 xx = *reinterpret_cast<const float4*>(src);
        f16x4 y = { (_Float16)xx.x, (_Float16)xx.y, (_Float16)xx.z, (_Float16)xx.w };
        *reinterpret_cast<f16x4*>(dst) = y;
    } else if (bid < 22528) {
        const int row = bid - 18432;
        const int e = row >> 8, rem = row & 255, half = rem >> 7, mi = rem & 127;
        const float* src = (half ? eu : eg) + ((size_t)(e * 128 + mi)) * 2048;
        const int c = threadIdx.x * 8;
        float4 v0 = *reinterpret_cast<const float4*>(src + c);
        float4 v1 = *reinterpret_cast<const float4*>(src + c + 4);
        f16x8 ov = { (_Float16)v0.x,(_Float16)v0.y,(_Float16)v0.z,(_Float16)v0.w,
                     (_Float16)v1.x,(_Float16)v1.y,(_Float16)v1.z,(_Float16)v1.w };
        *reinterpret_cast<f16x8*>(guw + (size_t)row * 2048 + c) = ov;
    } else if (bid < 26624) {
        int t = (bid - 22528) * 256 + threadIdx.x;
        int mi4 = (t & 31) * 4;
        int dm = (t >> 5) & 2047;
        int e = t >> 16;
        float4 vv = *reinterpret_cast<const float4*>(edw + (((size_t)e * 2048 + dm) << 7) + mi4);
        f16x4 ov = { (_Float16)vv.x, (_Float16)vv.y, (_Float16)vv.z, (_Float16)vv.w };
        *reinterpret_cast<f16x4*>(dwc + ((size_t)dm << 11) + e * 128 + mi4) = ov;
    } else if (bid == 26624) {
        int i = threadIdx.x;
        _Float16 vv = (i < 16) ? (_Float16)1.0f : (_Float16)0.0f;
        f16x4 ov = { vv, vv, vv, vv };
        *reinterpret_cast<f16x4*>(ones16 + i * 4) = ov;
    } else {
        const int row = bid - 26625, tid = threadIdx.x;
        const float* xr = x + (size_t)row * 2048;
        float4 a = *reinterpret_cast<const float4*>(xr + tid * 8);
        float4 b = *reinterpret_cast<const float4*>(xr + tid * 8 + 4);
        float ss = a.x*a.x + a.y*a.y + a.z*a.z + a.w*a.w
                 + b.x*b.x + b.y*b.y + b.z*b.z + b.w*b.w;
        #pragma unroll
        for (int m = 1; m < 64; m <<= 1) ss += __shfl_xor(ss, m);
        __shared__ float red[4];
        if ((tid & 63) == 0) red[tid >> 6] = ss;
        __syncthreads();
        float tot = red[0] + red[1] + red[2] + red[3];
        float r = rsqrtf(tot * (1.f / 2048.f) + 1e-6f);
        float4 wa = *reinterpret_cast<const float4*>(nattn + tid * 8);
        float4 wb = *reinterpret_cast<const float4*>(nattn + tid * 8 + 4);
        f16x8 hv = { (_Float16)(a.x*r*wa.x), (_Float16)(a.y*r*wa.y),
                     (_Float16)(a.z*r*wa.z), (_Float16)(a.w*r*wa.w),
                     (_Float16)(b.x*r*wb.x), (_Float16)(b.y*r*wb.y),
                     (_Float16)(b.z*r*wb.z), (_Float16)(b.w*r*wb.w) };
        *reinterpret_cast<f16x8*>(h + (size_t)row * 2048 + tid * 8) = hv;
    }
}

// ---------------------------------------------------------------- GEMM 128x128
__global__ __launch_bounds__(256) void k_gemm(
    const _Float16* __restrict__ A, int lda,
    const _Float16* __restrict__ W, int ldw,
    float* __restrict__ Cf, _Float16* __restrict__ Ch, int ldc,
    const float* __restrict__ resid, int K)
{
    __shared__ __align__(16) _Float16 As[3][128][32];
    __shared__ __align__(16) _Float16 Ws[3][128][32];
    const int r0 = blockIdx.x * 128, c0 = blockIdx.y * 128;
    const int tid = threadIdx.x, lane = tid & 63, wid = tid >> 6;
    const int wr = wid >> 1, wc = wid & 1;
    const int sr = lane >> 2;
    const int scs = ((lane & 3) ^ ((lane >> 3) & 3)) * 8;
    const int fr = lane & 15;
    const int rks = (((lane >> 4) ^ ((fr >> 1) & 3))) * 8;
    const f32x4 z4 = { 0.f, 0.f, 0.f, 0.f };
    f32x4 acc[4][4];
    #pragma unroll
    for (int i = 0; i < 4; i++)
        #pragma unroll
        for (int j = 0; j < 4; j++) acc[i][j] = z4;

    auto stage = [&](int bf, int k0) {
        #pragma unroll
        for (int i = 0; i < 2; i++) {
            int ch = wid * 2 + i;
            load16_lds(A + (size_t)(r0 + ch * 16 + sr) * lda + k0 + scs, &As[bf][ch * 16][0]);
            load16_lds(W + (size_t)(c0 + ch * 16 + sr) * ldw + k0 + scs, &Ws[bf][ch * 16][0]);
        }
    };

    const int nt = K >> 5;
    stage(0, 0);
    if (nt > 1) stage(1, 32);
    int cur = 0;
    for (int t = 0; t < nt; t++) {
        if (t < nt - 1) asm volatile("s_waitcnt vmcnt(4)" ::: "memory");
        else            asm volatile("s_waitcnt vmcnt(0)" ::: "memory");
        __builtin_amdgcn_s_barrier();
        f16x8 af[4], bf4[4];
        #pragma unroll
        for (int i = 0; i < 4; i++)
            af[i] = *reinterpret_cast<const f16x8*>(&As[cur][wr * 64 + i * 16 + fr][rks]);
        #pragma unroll
        for (int j = 0; j < 4; j++)
            bf4[j] = *reinterpret_cast<const f16x8*>(&Ws[cur][wc * 64 + j * 16 + fr][rks]);
        if (t + 2 < nt) stage((t + 2) % 3, (t + 2) << 5);
        __builtin_amdgcn_s_setprio(1);
        #pragma unroll
        for (int i = 0; i < 4; i++)
            #pragma unroll
            for (int j = 0; j < 4; j++)
                acc[i][j] = __builtin_amdgcn_mfma_f32_16x16x32_f16(af[i], bf4[j], acc[i][j], 0, 0, 0);
        __builtin_amdgcn_s_setprio(0);
        cur = (cur + 1) % 3;
    }
    #pragma unroll
    for (int i = 0; i < 4; i++) {
        const int rowb = r0 + wr * 64 + i * 16 + (lane >> 4) * 4;
        #pragma unroll
        for (int j = 0; j < 4; j++) {
            const int col = c0 + wc * 64 + j * 16 + fr;
            #pragma unroll
            for (int r = 0; r < 4; r++) {
                size_t idx = (size_t)(rowb + r) * ldc + col;
                float v = acc[i][j][r];
                if (resid) v += resid[idx];
                if (Ch) Ch[idx] = (_Float16)v;
                else    Cf[idx] = v;
            }
        }
    }
}

// ---------------------------------------------------------------- GEMM 256x256, 8 waves
// Modes: default f16 out; gu (wdense!=null): fused silu(g)*u*w_e -> ab;
// split-K (pf0!=null): K = per-slice depth, koff = z*K, f32 partial to pf0/pf1.
__global__ __launch_bounds__(512, 2) void k_gemm8(
    const _Float16* __restrict__ A, int lda,
    const _Float16* __restrict__ W, int ldw,
    _Float16* __restrict__ Ch, int ldc, int K,
    const float* __restrict__ wdense, _Float16* __restrict__ ab,
    float* __restrict__ pf0, float* __restrict__ pf1)
{
    __shared__ __align__(16) _Float16 As[3][256][32];
    __shared__ __align__(16) _Float16 Ws[3][256][32];
    const int r0 = blockIdx.x * 256, c0 = blockIdx.y * 256;
    const size_t koff = (size_t)blockIdx.z * K;
    const int tid = threadIdx.x, lane = tid & 63, wid = tid >> 6;
    const int wr = wid >> 2, wc = wid & 3;
    const int rA = lane >> 2;
    const int scs = ((lane & 3) ^ ((lane >> 3) & 3)) * 8;
    const int fr = lane & 15, fg = lane >> 4;
    const int rks = (((lane >> 4) ^ ((fr >> 1) & 3))) * 8;
    const f32x4 z4 = { 0.f, 0.f, 0.f, 0.f };
    f32x4 acc[8][4];
    #pragma unroll
    for (int i = 0; i < 8; i++)
        #pragma unroll
        for (int j = 0; j < 4; j++) acc[i][j] = z4;

    auto stage = [&](int bf, int k0) {
        #pragma unroll
        for (int i = 0; i < 2; i++) {
            load16_lds(A + (size_t)(r0 + i * 128 + wid * 16 + rA) * lda + koff + k0 + scs,
                       &As[bf][i * 128 + wid * 16][0]);
            load16_lds(W + (size_t)(c0 + i * 128 + wid * 16 + rA) * ldw + koff + k0 + scs,
                       &Ws[bf][i * 128 + wid * 16][0]);
        }
    };

    const int nt = K >> 5;
    stage(0, 0);
    if (nt > 1) stage(1, 32);
    int cur = 0;
    for (int t = 0; t < nt; t++) {
        if (t < nt - 1) asm volatile("s_waitcnt vmcnt(4)" ::: "memory");
        else            asm volatile("s_waitcnt vmcnt(0)" ::: "memory");
        __builtin_amdgcn_s_barrier();
        f16x8 af[8], bf4[4];
        #pragma unroll
        for (int i = 0; i < 8; i++)
            af[i] = *reinterpret_cast<const f16x8*>(&As[cur][wr * 128 + i * 16 + fr][rks]);
        #pragma unroll
        for (int j = 0; j < 4; j++)
            bf4[j] = *reinterpret_cast<const f16x8*>(&Ws[cur][wc * 64 + j * 16 + fr][rks]);
        if (t + 2 < nt) stage((t + 2) % 3, (t + 2) << 5);
        __builtin_amdgcn_s_setprio(1);
        #pragma unroll
        for (int i = 0; i < 8; i++)
            #pragma unroll
            for (int j = 0; j < 4; j++)
                acc[i][j] = __builtin_amdgcn_mfma_f32_16x16x32_f16(af[i], bf4[j], acc[i][j], 0, 0, 0);
        __builtin_amdgcn_s_setprio(0);
        cur = (cur + 1) % 3;
    }

    if (pf0) {                                   // split-K f32 partial
        float* Cf = blockIdx.z ? pf1 : pf0;
        #pragma unroll
        for (int i = 0; i < 8; i++) {
            const int rowb = r0 + wr * 128 + i * 16 + fg * 4;
            #pragma unroll
            for (int j = 0; j < 4; j++) {
                const int col = c0 + wc * 64 + j * 16 + fr;
                #pragma unroll
                for (int r = 0; r < 4; r++)
                    Cf[(size_t)(rowb + r) * ldc + col] = acc[i][j][r];
            }
        }
        return;
    }

    if (!wdense) {
        #pragma unroll
        for (int i = 0; i < 8; i++) {
            const int rowb = r0 + wr * 128 + i * 16 + fg * 4;
            #pragma unroll
            for (int j = 0; j < 4; j++) {
                const int col = c0 + wc * 64 + j * 16 + fr;
                #pragma unroll
                for (int r = 0; r < 4; r++)
                    Ch[(size_t)(rowb + r) * ldc + col] = (_Float16)acc[i][j][r];
            }
        }
        return;
    }

    _Float16* LgA = &As[0][0][0];
    _Float16* LgB = &Ws[0][0][0];
    auto lgp = [&](int row, int mi) -> _Float16* {
        return ((row < 128) ? LgA : LgB) + (size_t)(row & 127) * 136 + mi;
    };
    const int e = blockIdx.y;
    __syncthreads();
    if (wc < 2) {
        #pragma unroll
        for (int i = 0; i < 8; i++) {
            const int row = wr * 128 + i * 16 + fg * 4;
            #pragma unroll
            for (int j = 0; j < 4; j++) {
                const int mi = wc * 64 + j * 16 + fr;
                #pragma unroll
                for (int r = 0; r < 4; r++)
                    *lgp(row + r, mi) = (_Float16)acc[i][j][r];
            }
        }
    }
    __syncthreads();
    if (wc >= 2) {
        #pragma unroll
        for (int i = 0; i < 8; i++) {
            const int row = wr * 128 + i * 16 + fg * 4;
            #pragma unroll
            for (int j = 0; j < 4; j++) {
                const int mi = (wc - 2) * 64 + j * 16 + fr;
                #pragma unroll
                for (int r = 0; r < 4; r++) {
                    float g = (float)*lgp(row + r, mi);
                    float sil = g / (1.f + __expf(-g));
                    *lgp(row + r, mi) = (_Float16)(sil * acc[i][j][r]);
                }
            }
        }
    }
    __syncthreads();
    #pragma unroll
    for (int pass = 0; pass < 8; pass++) {
        int cid = pass * 512 + tid;
        int row = cid >> 4, col8 = cid & 15;
        f16x8 v = *reinterpret_cast<const f16x8*>(
            ((row < 128) ? LgA : LgB) + (size_t)(row & 127) * 136 + col8 * 8);
        float wv = wdense[(size_t)e * 4096 + r0 + row];
        f16x8 o;
        #pragma unroll
        for (int j = 0; j < 8; j++) o[j] = (_Float16)((float)v[j] * wv);
        *reinterpret_cast<f16x8*>(ab + (size_t)(r0 + row) * 2048 + e * 128 + col8 * 8) = o;
    }
}

// ---------------------------------------------------------------- O-proj epilogue
// x2 = p0 + p1 + x; hm = rmsnorm(x2) * nmlp.  (x2 may alias p1: same-index RW.)
__global__ __launch_bounds__(256) void k_oepi(
    const float* __restrict__ p0, const float* __restrict__ p1,
    const float* __restrict__ x, const float* __restrict__ nmlp,
    float* __restrict__ x2, _Float16* __restrict__ hm)
{
    const int row = blockIdx.x, tid = threadIdx.x;
    const size_t base = (size_t)row * 2048 + tid * 8;
    float4 a0 = *reinterpret_cast<const float4*>(p0 + base);
    float4 a1 = *reinterpret_cast<const float4*>(p0 + base + 4);
    float4 b0 = *reinterpret_cast<const float4*>(p1 + base);
    float4 b1 = *reinterpret_cast<const float4*>(p1 + base + 4);
    float4 c0 = *reinterpret_cast<const float4*>(x + base);
    float4 c1 = *reinterpret_cast<const float4*>(x + base + 4);
    float4 v0 = { a0.x + b0.x + c0.x, a0.y + b0.y + c0.y,
                  a0.z + b0.z + c0.z, a0.w + b0.w + c0.w };
    float4 v1 = { a1.x + b1.x + c1.x, a1.y + b1.y + c1.y,
                  a1.z + b1.z + c1.z, a1.w + b1.w + c1.w };
    float ss = v0.x*v0.x + v0.y*v0.y + v0.z*v0.z + v0.w*v0.w
             + v1.x*v1.x + v1.y*v1.y + v1.z*v1.z + v1.w*v1.w;
    #pragma unroll
    for (int m = 1; m < 64; m <<= 1) ss += __shfl_xor(ss, m);
    __shared__ float red[4];
    if ((tid & 63) == 0) red[tid >> 6] = ss;
    __syncthreads();
    float tot = red[0] + red[1] + red[2] + red[3];
    float r = rsqrtf(tot * (1.f / 2048.f) + 1e-6f);
    *reinterpret_cast<float4*>(x2 + base) = v0;
    *reinterpret_cast<float4*>(x2 + base + 4) = v1;
    float4 wa = *reinterpret_cast<const float4*>(nmlp + tid * 8);
    float4 wb = *reinterpret_cast<const float4*>(nmlp + tid * 8 + 4);
    f16x8 hv = { (_Float16)(v0.x*r*wa.x), (_Float16)(v0.y*r*wa.y),
                 (_Float16)(v0.z*r*wa.z), (_Float16)(v0.w*r*wa.w),
                 (_Float16)(v1.x*r*wb.x), (_Float16)(v1.y*r*wb.y),
                 (_Float16)(v1.z*r*wb.z), (_Float16)(v1.w*r*wb.w) };
    *reinterpret_cast<f16x8*>(hm + (size_t)row * 2048 + tid * 8) = hv;
}

// ------------------------------------------- per-head RMSNorm + RoPE + V-transpose
__global__ __launch_bounds__(256) void k_qkv_post(
    const _Float16* __restrict__ qkv,
    const float* __restrict__ cosb, const float* __restrict__ sinb,
    const float* __restrict__ qn_w, const float* __restrict__ kn_w,
    _Float16* __restrict__ qh, _Float16* __restrict__ kh,
    _Float16* __restrict__ vth)
{
    if (blockIdx.y == 9) {
        const int unit = blockIdx.x;
        if (unit >= 512) return;
        const int bkv = unit >> 5, rem = unit & 31;
        const int l0 = (rem >> 1) * 64, d0 = (rem & 1) * 64;
        const int b = bkv >> 2, kv = bkv & 3;
        __shared__ _Float16 T[64][72];
        const int t = threadIdx.x;
        const int r = t >> 3, c8 = (t & 7) * 8;
        #pragma unroll
        for (int rr = 0; rr < 2; rr++) {
            int l = l0 + r + rr * 32;
            *reinterpret_cast<f16x8*>(&T[r + rr * 32][c8]) =
                *reinterpret_cast<const f16x8*>(
                    qkv + (size_t)(b * 1024 + l) * 5120 + 4608 + kv * 128 + d0 + c8);
        }
        __syncthreads();
        #pragma unroll
        for (int rr = 0; rr < 2; rr++) {
            int d = d0 + r + rr * 32;
            f16x8 v;
            #pragma unroll
            for (int j = 0; j < 8; j++) v[j] = T[c8 + j][r + rr * 32];
            *reinterpret_cast<f16x8*>(vth + ((size_t)(bkv * 128 + d)) * 1024 + l0 + c8) = v;
        }
        return;
    }
    const int tok = blockIdx.x;
    const int u = blockIdx.y * 4 + (threadIdx.x >> 6);
    const int lane = threadIdx.x & 63;
    const int b = tok >> 10, l = tok & 1023;
    const float SCL = 0.12752887074166638f;   // 1/sqrt(128) * log2(e)
    const float c0 = cosb[(size_t)tok * 128 + lane];
    const float c1 = cosb[(size_t)tok * 128 + lane + 64];
    const float s0 = sinb[(size_t)tok * 128 + lane];
    const float s1 = sinb[(size_t)tok * 128 + lane + 64];
    if (u < 32) {
        const _Float16* base = qkv + (size_t)tok * 5120 + u * 128;
        float v0 = (float)base[lane], v1 = (float)base[lane + 64];
        float ss = v0 * v0 + v1 * v1;
        #pragma unroll
        for (int m = 1; m < 64; m <<= 1) ss += __shfl_xor(ss, m);
        float rms = rsqrtf(ss * (1.f / 128.f) + 1e-6f);
        float n0 = v0 * rms * qn_w[lane], n1 = v1 * rms * qn_w[lane + 64];
        _Float16* o = qh + (size_t)tok * 4096 + u * 128;
        o[lane]      = (_Float16)(SCL * (c0 * n0 - s0 * n1));
        o[lane + 64] = (_Float16)(SCL * (c1 * n1 + s1 * n0));
    } else {
        const int kvh = u - 32;
        const _Float16* base = qkv + (size_t)tok * 5120 + 4096 + kvh * 128;
        float v0 = (float)base[lane], v1 = (float)base[lane + 64];
        float ss = v0 * v0 + v1 * v1;
        #pragma unroll
        for (int m = 1; m < 64; m <<= 1) ss += __shfl_xor(ss, m);
        float rms = rsqrtf(ss * (1.f / 128.f) + 1e-6f);
        float n0 = v0 * rms * kn_w[lane], n1 = v1 * rms * kn_w[lane + 64];
        _Float16* o = kh + (((size_t)(b * 4 + kvh)) * 1024 + l) * 128;
        o[lane]      = (_Float16)(c0 * n0 - s0 * n1);
        o[lane + 64] = (_Float16)(c1 * n1 + s1 * n0);
    }
}

// ---------------------------------------------------------------- attention
__global__ __launch_bounds__(512) void k_attn(
    const _Float16* __restrict__ qh, const _Float16* __restrict__ kh,
    const _Float16* __restrict__ vth, const _Float16* __restrict__ ones16,
    _Float16* __restrict__ oh)
{
    const int bh = blockIdx.x;
    const int qb = 3 - blockIdx.y;
    const int b = bh >> 5, h = bh & 31, kv = h >> 3;
    const int tid = threadIdx.x, lane = tid & 63, wid = tid >> 6;
    const int fr = lane & 15, fg = lane >> 4;
    const int q0w = qb * 256 + wid * 32;

    __shared__ __align__(16) _Float16 Ks[2][64][128];
    __shared__ __align__(16) _Float16 Vs[2][128][64];
    __shared__ __align__(16) _Float16 Vones[16][64];
    __shared__ __align__(16) _Float16 Ps[8][32][72];

    const _Float16* kb = kh + ((size_t)(b * 4 + kv)) * 1024 * 128;
    const _Float16* vb = vth + ((size_t)(b * 4 + kv)) * 128 * 1024;

    auto stage = [&](int nb, int key0) {
        #pragma unroll
        for (int i = 0; i < 2; i++) {
            int rr = wid * 8 + i * 4 + (lane >> 4);
            int c16 = (lane & 15) ^ (rr & 15);
            load16_lds(kb + (size_t)(key0 + rr) * 128 + c16 * 8,
                       &Ks[nb][0][0] + (wid * 8 + i * 4) * 128);
        }
        #pragma unroll
        for (int i = 0; i < 2; i++) {
            int rr = wid * 16 + i * 8 + (lane >> 3);
            int c16 = (lane & 7) ^ (rr & 7);
            load16_lds(vb + (size_t)rr * 1024 + key0 + c16 * 8,
                       &Vs[nb][0][0] + (wid * 16 + i * 8) * 64);
        }
    };

    f16x8 aq[2][4];
    #pragma unroll
    for (int mi = 0; mi < 2; mi++) {
        const _Float16* qbase =
            qh + ((size_t)(b * 1024 + q0w + mi * 16 + fr)) * 4096 + h * 128;
        #pragma unroll
        for (int kk = 0; kk < 4; kk++)
            aq[mi][kk] = *reinterpret_cast<const f16x8*>(qbase + kk * 32 + fg * 8);
    }
    if (wid == 0) {
        #pragma unroll
        for (int i = 0; i < 2; i++)
            load16_lds(ones16 + (size_t)(lane + i * 64) * 8, &Vones[0][0] + i * 512);
    }
    stage(0, 0);

    const f32x4 z4 = { 0.f, 0.f, 0.f, 0.f };
    f32x4 oacc[2][9];
    #pragma unroll
    for (int mi = 0; mi < 2; mi++)
        #pragma unroll
        for (int dj = 0; dj < 9; dj++) oacc[mi][dj] = z4;

    const int ntiles = qb * 4 + 4;
    int cb = 0;
    for (int kt = 0; kt < ntiles; kt++) {
        const int key0 = kt * 64;
        asm volatile("s_waitcnt vmcnt(0)" ::: "memory");
        __builtin_amdgcn_s_barrier();
        if (kt + 1 < ntiles) stage(cb ^ 1, key0 + 64);

        if (key0 <= q0w + 31) {
            f32x4 sc[2][4];
            #pragma unroll
            for (int mi = 0; mi < 2; mi++)
                #pragma unroll
                for (int j = 0; j < 4; j++) sc[mi][j] = z4;
            __builtin_amdgcn_s_setprio(1);
            #pragma unroll
            for (int j = 0; j < 4; j++)
                #pragma unroll
                for (int kk = 0; kk < 4; kk++) {
                    f16x8 bk = *reinterpret_cast<const f16x8*>(
                        &Ks[cb][0][0] + (j * 16 + fr) * 128 + (((kk * 4 + fg) ^ fr) * 8));
                    #pragma unroll
                    for (int mi = 0; mi < 2; mi++)
                        sc[mi][j] = __builtin_amdgcn_mfma_f32_16x16x32_f16(
                            aq[mi][kk], bk, sc[mi][j], 0, 0, 0);
                }
            __builtin_amdgcn_s_setprio(0);

            const bool maskt = (key0 + 63 > q0w);
            #pragma unroll
            for (int mi = 0; mi < 2; mi++)
                #pragma unroll
                for (int j = 0; j < 4; j++) {
                    const int key = key0 + j * 16 + fr;
                    #pragma unroll
                    for (int r = 0; r < 4; r++) {
                        float v = sc[mi][j][r];
                        if (maskt && key > q0w + mi * 16 + fg * 4 + r) v = -1e30f;
                        Ps[wid][mi * 16 + fg * 4 + r][j * 16 + fr] =
                            (_Float16)__builtin_amdgcn_exp2f(v - 8.f);
                    }
                }

            __builtin_amdgcn_s_setprio(1);
            #pragma unroll
            for (int ks = 0; ks < 2; ks++) {
                f16x8 ap0 = *reinterpret_cast<const f16x8*>(
                    &Ps[wid][fr][ks * 32 + fg * 8]);
                f16x8 ap1 = *reinterpret_cast<const f16x8*>(
                    &Ps[wid][16 + fr][ks * 32 + fg * 8]);
                #pragma unroll
                for (int dj = 0; dj < 8; dj++) {
                    f16x8 bv = *reinterpret_cast<const f16x8*>(
                        &Vs[cb][0][0] + (dj * 16 + fr) * 64 + (((ks * 4 + fg) ^ (fr & 7)) * 8));
                    oacc[0][dj] = __builtin_amdgcn_mfma_f32_16x16x32_f16(ap0, bv, oacc[0][dj], 0, 0, 0);
                    oacc[1][dj] = __builtin_amdgcn_mfma_f32_16x16x32_f16(ap1, bv, oacc[1][dj], 0, 0, 0);
                }
                f16x8 bo = *reinterpret_cast<const f16x8*>(
                    &Vones[0][0] + fr * 64 + (((ks * 4 + fg) ^ (fr & 7)) * 8));
                oacc[0][8] = __builtin_amdgcn_mfma_f32_16x16x32_f16(ap0, bo, oacc[0][8], 0, 0, 0);
                oacc[1][8] = __builtin_amdgcn_mfma_f32_16x16x32_f16(ap1, bo, oacc[1][8], 0, 0, 0);
            }
            __builtin_amdgcn_s_setprio(0);
        }
        cb ^= 1;
    }

    #pragma unroll
    for (int mi = 0; mi < 2; mi++) {
        float inv[4];
        #pragma unroll
        for (int r = 0; r < 4; r++) {
            float l = __shfl(oacc[mi][8][r], lane & 48);
            inv[r] = 1.f / l;
        }
        #pragma unroll
        for (int dj = 0; dj < 8; dj++)
            #pragma unroll
            for (int r = 0; r < 4; r++)
                oh[((size_t)(b * 1024 + q0w + mi * 16 + fg * 4 + r)) * 4096
                   + h * 128 + dj * 16 + fr] = (_Float16)(oacc[mi][dj][r] * inv[r]);
    }
}

// ---------------------------------------------------------------- router (inline rmsnorm from x2)
__global__ __launch_bounds__(256) void k_router(
    const float* __restrict__ x2, const float* __restrict__ wm,
    const float* __restrict__ rw, float* __restrict__ wdense)
{
    const int tok = blockIdx.x * 4 + (threadIdx.x >> 6);
    const int lane = threadIdx.x & 63;
    __shared__ float lg[4][16];
    const float* hr = x2 + (size_t)tok * 2048;
    float vals[32];
    float ss = 0.f;
    #pragma unroll
    for (int i = 0; i < 32; i++) { float v = hr[i * 64 + lane]; vals[i] = v; ss += v * v; }
    #pragma unroll
    for (int m = 1; m < 64; m <<= 1) ss += __shfl_xor(ss, m);
    float r = rsqrtf(ss * (1.f / 2048.f) + 1e-6f);
    #pragma unroll
    for (int i = 0; i < 32; i++) vals[i] *= r * wm[i * 64 + lane];
    for (int e = 0; e < 16; e++) {
        float acc = 0.f;
        #pragma unroll
        for (int i = 0; i < 32; i++) acc += vals[i] * rw[(size_t)e * 2048 + i * 64 + lane];
        #pragma unroll
        for (int m = 1; m < 64; m <<= 1) acc += __shfl_xor(acc, m);
        if (lane == 0) lg[threadIdx.x >> 6][e] = acc;
    }
    __syncthreads();
    if (lane == 0) {
        float* l = lg[threadIdx.x >> 6];
        float mx = l[0];
        for (int e = 1; e < 16; e++) mx = fmaxf(mx, l[e]);
        float p[16]; float sum = 0.f;
        for (int e = 0; e < 16; e++) { p[e] = expf(l[e] - mx); sum += p[e]; }
        for (int e = 0; e < 16; e++) p[e] /= sum;
        bool sel[16]; for (int e = 0; e < 16; e++) sel[e] = false;
        float ssum = 0.f;
        for (int t = 0; t < 8; t++) {
            int bi = -1; float bv = -1.f;
            for (int e = 0; e < 16; e++) if (!sel[e] && p[e] > bv) { bv = p[e]; bi = e; }
            sel[bi] = true; ssum += bv;
        }
        for (int e = 0; e < 16; e++)
            wdense[(size_t)e * 4096 + tok] = sel[e] ? p[e] / ssum : 0.f;
    }
}

// ---------------------------------------------------------------- launch

extern "C" void kernel_launch(void* const* d_in, const int* in_sizes, int n_in,
                              void* d_out, int out_size, void* d_ws, size_t ws_size,
                              hipStream_t stream)
{
    const float* x        = (const float*)d_in[0];
    const float* cosb     = (const float*)d_in[1];
    const float* sinb     = (const float*)d_in[2];
    const float* nattn    = (const float*)d_in[3];
    const float* q_w      = (const float*)d_in[4];
    const float* k_w      = (const float*)d_in[5];
    const float* v_w      = (const float*)d_in[6];
    const float* qn_w     = (const float*)d_in[7];
    const float* kn_w     = (const float*)d_in[8];
    const float* o_w      = (const float*)d_in[9];
    const float* nmlp     = (const float*)d_in[10];
    const float* router_w = (const float*)d_in[11];
    const float* egw      = (const float*)d_in[12];
    const float* euw      = (const float*)d_in[13];
    const float* edw      = (const float*)d_in[14];

    char* w = (char*)d_ws;
    _Float16* qkvw_h = (_Float16*)(w + 0);          // 20.97 MB
    _Float16* ow_h   = (_Float16*)(w + 20971520);   // 16.78 MB
    _Float16* guw_h  = (_Float16*)(w + 37748736);   // 16.78 MB
    _Float16* dwc_h  = (_Float16*)(w + 54525952);   //  8.39 MB
    _Float16* h_h    = (_Float16*)(w + 62914560);   // 16.78 MB (aliased hm_h)
    _Float16* hm_h   = h_h;
    float*    x2     = (float*)(w + 79691776);      // 33.55 MB (aliases P1)
    float*    p1_f   = x2;
    _Float16* qkv_h  = (_Float16*)(w + 113246208);  // 41.94 MB (alias o_h, ab_h)
    _Float16* o_h    = qkv_h;
    _Float16* ab_h   = qkv_h;
    _Float16* q_h    = (_Float16*)(w + 155189248);  // 33.55 MB (aliases P0)
    float*    p0_f   = (float*)(w + 155189248);
    _Float16* k_h    = (_Float16*)(w + 188743680);  //  4.19 MB
    _Float16* vt_h   = (_Float16*)(w + 192937984);  //  4.19 MB
    float*    wdense = (float*)(w + 197132288);     //  0.26 MB
    _Float16* ones_h = (_Float16*)(w + 197394432);  //  2 KB

    k_castall<<<30721, 256, 0, stream>>>(q_w, k_w, v_w, o_w, egw, euw, edw, x, nattn,
                                         qkvw_h, ow_h, guw_h, dwc_h, ones_h, h_h);
    k_gemm8<<<dim3(16, 16), 512, 0, stream>>>(h_h, 2048, qkvw_h, 2048, qkv_h, 5120, 2048,
                                              nullptr, nullptr, nullptr, nullptr);
    k_gemm<<<dim3(32, 8), 256, 0, stream>>>(h_h, 2048, qkvw_h + (size_t)4096 * 2048, 2048,
                                            nullptr, qkv_h + 4096, 5120, nullptr, 2048);
    k_qkv_post<<<dim3(4096, 10), 256, 0, stream>>>(qkv_h, cosb, sinb, qn_w, kn_w,
                                                   q_h, k_h, vt_h);
    k_attn<<<dim3(128, 4), 512, 0, stream>>>(q_h, k_h, vt_h, ones_h, o_h);
    // O-proj as split-K 256^2 GEMM (grid 16x8x2 = 256 blocks), f32 partials
    k_gemm8<<<dim3(16, 8, 2), 512, 0, stream>>>(o_h, 4096, ow_h, 4096,
                                                nullptr, 2048, 2048,
                                                nullptr, nullptr, p0_f, p1_f);
    // epilogue: x2 = P0+P1+x, hm = rmsnorm(x2)  (x2 aliases P1 elementwise)
    k_oepi<<<4096, 256, 0, stream>>>(p0_f, p1_f, x, nmlp, x2, hm_h);
    k_router<<<1024, 256, 0, stream>>>(x2, nmlp, router_w, wdense);
    k_gemm8<<<dim3(16, 16), 512, 0, stream>>>(hm_h, 2048, guw_h, 2048, nullptr, 0, 2048,
                                              wdense, ab_h, nullptr, nullptr);
    k_gemm<<<dim3(32, 16), 256, 0, stream>>>(ab_h, 2048, dwc_h, 2048,
                                             (float*)d_out, nullptr, 2048, x2, 2048);

    (void)in_sizes; (void)n_in; (void)out_size; (void)ws_size;
}

// Round 18
// 469.076 us; speedup vs baseline: 1.0304x; 1.0244x over previous
//
#include <hip/hip_runtime.h>
#include <stdint.h>

typedef _Float16 f16x8 __attribute__((ext_vector_type(8)));
typedef _Float16 f16x4 __attribute__((ext_vector_type(4)));
typedef float    f32x4 __attribute__((ext_vector_type(4)));

__device__ __forceinline__ void load16_lds(const _Float16* g, _Float16* l) {
    __builtin_amdgcn_global_load_lds(
        (const __attribute__((address_space(1))) void*)g,
        (__attribute__((address_space(3))) void*)l, 16, 0, 0);
}

// ---------------------------------------------------------------- fused casts + attn rmsnorm
__global__ __launch_bounds__(256) void k_castall(
    const float* __restrict__ q, const float* __restrict__ k,
    const float* __restrict__ v, const float* __restrict__ o,
    const float* __restrict__ eg, const float* __restrict__ eu,
    const float* __restrict__ edw,
    const float* __restrict__ x, const float* __restrict__ nattn,
    _Float16* __restrict__ qkvw, _Float16* __restrict__ ow,
    _Float16* __restrict__ guw, _Float16* __restrict__ dwc,
    _Float16* __restrict__ ones16, _Float16* __restrict__ h)
{
    const int bid = blockIdx.x;
    if (bid < 18432) {
        size_t i = ((size_t)bid * 256 + threadIdx.x) * 4;
        const float* src; _Float16* dst;
        if (i < 8388608)        { src = q + i;             dst = qkvw + i; }
        else if (i < 9437184)   { src = k + (i - 8388608); dst = qkvw + i; }
        else if (i < 10485760)  { src = v + (i - 9437184); dst = qkvw + i; }
        else                    { src = o + (i - 10485760); dst = ow + (i - 10485760); }
        float4 xx = *reinterpret_cast<const float4*>(src);
        f16x4 y = { (_Float16)xx.x, (_Float16)xx.y, (_Float16)xx.z, (_Float16)xx.w };
        *reinterpret_cast<f16x4*>(dst) = y;
    } else if (bid < 22528) {
        const int row = bid - 18432;
        const int e = row >> 8, rem = row & 255, half = rem >> 7, mi = rem & 127;
        const float* src = (half ? eu : eg) + ((size_t)(e * 128 + mi)) * 2048;
        const int c = threadIdx.x * 8;
        float4 v0 = *reinterpret_cast<const float4*>(src + c);
        float4 v1 = *reinterpret_cast<const float4*>(src + c + 4);
        f16x8 ov = { (_Float16)v0.x,(_Float16)v0.y,(_Float16)v0.z,(_Float16)v0.w,
                     (_Float16)v1.x,(_Float16)v1.y,(_Float16)v1.z,(_Float16)v1.w };
        *reinterpret_cast<f16x8*>(guw + (size_t)row * 2048 + c) = ov;
    } else if (bid < 26624) {
        int t = (bid - 22528) * 256 + threadIdx.x;
        int mi4 = (t & 31) * 4;
        int dm = (t >> 5) & 2047;
        int e = t >> 16;
        float4 vv = *reinterpret_cast<const float4*>(edw + (((size_t)e * 2048 + dm) << 7) + mi4);
        f16x4 ov = { (_Float16)vv.x, (_Float16)vv.y, (_Float16)vv.z, (_Float16)vv.w };
        *reinterpret_cast<f16x4*>(dwc + ((size_t)dm << 11) + e * 128 + mi4) = ov;
    } else if (bid == 26624) {
        int i = threadIdx.x;
        _Float16 vv = (i < 16) ? (_Float16)1.0f : (_Float16)0.0f;
        f16x4 ov = { vv, vv, vv, vv };
        *reinterpret_cast<f16x4*>(ones16 + i * 4) = ov;
    } else {
        const int row = bid - 26625, tid = threadIdx.x;
        const float* xr = x + (size_t)row * 2048;
        float4 a = *reinterpret_cast<const float4*>(xr + tid * 8);
        float4 b = *reinterpret_cast<const float4*>(xr + tid * 8 + 4);
        float ss = a.x*a.x + a.y*a.y + a.z*a.z + a.w*a.w
                 + b.x*b.x + b.y*b.y + b.z*b.z + b.w*b.w;
        #pragma unroll
        for (int m = 1; m < 64; m <<= 1) ss += __shfl_xor(ss, m);
        __shared__ float red[4];
        if ((tid & 63) == 0) red[tid >> 6] = ss;
        __syncthreads();
        float tot = red[0] + red[1] + red[2] + red[3];
        float r = rsqrtf(tot * (1.f / 2048.f) + 1e-6f);
        float4 wa = *reinterpret_cast<const float4*>(nattn + tid * 8);
        float4 wb = *reinterpret_cast<const float4*>(nattn + tid * 8 + 4);
        f16x8 hv = { (_Float16)(a.x*r*wa.x), (_Float16)(a.y*r*wa.y),
                     (_Float16)(a.z*r*wa.z), (_Float16)(a.w*r*wa.w),
                     (_Float16)(b.x*r*wb.x), (_Float16)(b.y*r*wb.y),
                     (_Float16)(b.z*r*wb.z), (_Float16)(b.w*r*wb.w) };
        *reinterpret_cast<f16x8*>(h + (size_t)row * 2048 + tid * 8) = hv;
    }
}

// ---------------------------------------------------------------- GEMM 128x128
__global__ __launch_bounds__(256) void k_gemm(
    const _Float16* __restrict__ A, int lda,
    const _Float16* __restrict__ W, int ldw,
    float* __restrict__ Cf, _Float16* __restrict__ Ch, int ldc,
    const float* __restrict__ resid, int K)
{
    __shared__ __align__(16) _Float16 As[3][128][32];
    __shared__ __align__(16) _Float16 Ws[3][128][32];
    const int r0 = blockIdx.x * 128, c0 = blockIdx.y * 128;
    const int tid = threadIdx.x, lane = tid & 63, wid = tid >> 6;
    const int wr = wid >> 1, wc = wid & 1;
    const int sr = lane >> 2;
    const int scs = ((lane & 3) ^ ((lane >> 3) & 3)) * 8;
    const int fr = lane & 15;
    const int rks = (((lane >> 4) ^ ((fr >> 1) & 3))) * 8;
    const f32x4 z4 = { 0.f, 0.f, 0.f, 0.f };
    f32x4 acc[4][4];
    #pragma unroll
    for (int i = 0; i < 4; i++)
        #pragma unroll
        for (int j = 0; j < 4; j++) acc[i][j] = z4;

    auto stage = [&](int bf, int k0) {
        #pragma unroll
        for (int i = 0; i < 2; i++) {
            int ch = wid * 2 + i;
            load16_lds(A + (size_t)(r0 + ch * 16 + sr) * lda + k0 + scs, &As[bf][ch * 16][0]);
            load16_lds(W + (size_t)(c0 + ch * 16 + sr) * ldw + k0 + scs, &Ws[bf][ch * 16][0]);
        }
    };

    const int nt = K >> 5;
    stage(0, 0);
    if (nt > 1) stage(1, 32);
    int cur = 0;
    for (int t = 0; t < nt; t++) {
        if (t < nt - 1) asm volatile("s_waitcnt vmcnt(4)" ::: "memory");
        else            asm volatile("s_waitcnt vmcnt(0)" ::: "memory");
        __builtin_amdgcn_s_barrier();
        f16x8 af[4], bf4[4];
        #pragma unroll
        for (int i = 0; i < 4; i++)
            af[i] = *reinterpret_cast<const f16x8*>(&As[cur][wr * 64 + i * 16 + fr][rks]);
        #pragma unroll
        for (int j = 0; j < 4; j++)
            bf4[j] = *reinterpret_cast<const f16x8*>(&Ws[cur][wc * 64 + j * 16 + fr][rks]);
        if (t + 2 < nt) stage((t + 2) % 3, (t + 2) << 5);
        __builtin_amdgcn_s_setprio(1);
        #pragma unroll
        for (int i = 0; i < 4; i++)
            #pragma unroll
            for (int j = 0; j < 4; j++)
                acc[i][j] = __builtin_amdgcn_mfma_f32_16x16x32_f16(af[i], bf4[j], acc[i][j], 0, 0, 0);
        __builtin_amdgcn_s_setprio(0);
        cur = (cur + 1) % 3;
    }
    #pragma unroll
    for (int i = 0; i < 4; i++) {
        const int rowb = r0 + wr * 64 + i * 16 + (lane >> 4) * 4;
        #pragma unroll
        for (int j = 0; j < 4; j++) {
            const int col = c0 + wc * 64 + j * 16 + fr;
            #pragma unroll
            for (int r = 0; r < 4; r++) {
                size_t idx = (size_t)(rowb + r) * ldc + col;
                float v = acc[i][j][r];
                if (resid) v += resid[idx];
                if (Ch) Ch[idx] = (_Float16)v;
                else    Cf[idx] = v;
            }
        }
    }
}

// ---------------------------------------------------------------- GEMM 256x256, 8 waves
// Modes: default f16 out (Ch; split-K via blockIdx.z: koff=z*K, Ch2 for z=1);
// gu (wdense!=null): fused silu(g)*u*w_e -> ab.
__global__ __launch_bounds__(512, 2) void k_gemm8(
    const _Float16* __restrict__ A, int lda,
    const _Float16* __restrict__ W, int ldw,
    _Float16* __restrict__ Ch, _Float16* __restrict__ Ch2, int ldc, int K,
    const float* __restrict__ wdense, _Float16* __restrict__ ab)
{
    __shared__ __align__(16) _Float16 As[3][256][32];
    __shared__ __align__(16) _Float16 Ws[3][256][32];
    const int r0 = blockIdx.x * 256, c0 = blockIdx.y * 256;
    const size_t koff = (size_t)blockIdx.z * K;
    const int tid = threadIdx.x, lane = tid & 63, wid = tid >> 6;
    const int wr = wid >> 2, wc = wid & 3;
    const int rA = lane >> 2;
    const int scs = ((lane & 3) ^ ((lane >> 3) & 3)) * 8;
    const int fr = lane & 15, fg = lane >> 4;
    const int rks = (((lane >> 4) ^ ((fr >> 1) & 3))) * 8;
    const f32x4 z4 = { 0.f, 0.f, 0.f, 0.f };
    f32x4 acc[8][4];
    #pragma unroll
    for (int i = 0; i < 8; i++)
        #pragma unroll
        for (int j = 0; j < 4; j++) acc[i][j] = z4;

    auto stage = [&](int bf, int k0) {
        #pragma unroll
        for (int i = 0; i < 2; i++) {
            load16_lds(A + (size_t)(r0 + i * 128 + wid * 16 + rA) * lda + koff + k0 + scs,
                       &As[bf][i * 128 + wid * 16][0]);
            load16_lds(W + (size_t)(c0 + i * 128 + wid * 16 + rA) * ldw + koff + k0 + scs,
                       &Ws[bf][i * 128 + wid * 16][0]);
        }
    };

    const int nt = K >> 5;
    stage(0, 0);
    if (nt > 1) stage(1, 32);
    int cur = 0;
    for (int t = 0; t < nt; t++) {
        if (t < nt - 1) asm volatile("s_waitcnt vmcnt(4)" ::: "memory");
        else            asm volatile("s_waitcnt vmcnt(0)" ::: "memory");
        __builtin_amdgcn_s_barrier();
        f16x8 af[8], bf4[4];
        #pragma unroll
        for (int i = 0; i < 8; i++)
            af[i] = *reinterpret_cast<const f16x8*>(&As[cur][wr * 128 + i * 16 + fr][rks]);
        #pragma unroll
        for (int j = 0; j < 4; j++)
            bf4[j] = *reinterpret_cast<const f16x8*>(&Ws[cur][wc * 64 + j * 16 + fr][rks]);
        if (t + 2 < nt) stage((t + 2) % 3, (t + 2) << 5);
        __builtin_amdgcn_s_setprio(1);
        #pragma unroll
        for (int i = 0; i < 8; i++)
            #pragma unroll
            for (int j = 0; j < 4; j++)
                acc[i][j] = __builtin_amdgcn_mfma_f32_16x16x32_f16(af[i], bf4[j], acc[i][j], 0, 0, 0);
        __builtin_amdgcn_s_setprio(0);
        cur = (cur + 1) % 3;
    }

    if (!wdense) {
        _Float16* Cd = blockIdx.z ? Ch2 : Ch;
        #pragma unroll
        for (int i = 0; i < 8; i++) {
            const int rowb = r0 + wr * 128 + i * 16 + fg * 4;
            #pragma unroll
            for (int j = 0; j < 4; j++) {
                const int col = c0 + wc * 64 + j * 16 + fr;
                #pragma unroll
                for (int r = 0; r < 4; r++)
                    Cd[(size_t)(rowb + r) * ldc + col] = (_Float16)acc[i][j][r];
            }
        }
        return;
    }

    _Float16* LgA = &As[0][0][0];
    _Float16* LgB = &Ws[0][0][0];
    auto lgp = [&](int row, int mi) -> _Float16* {
        return ((row < 128) ? LgA : LgB) + (size_t)(row & 127) * 136 + mi;
    };
    const int e = blockIdx.y;
    __syncthreads();
    if (wc < 2) {
        #pragma unroll
        for (int i = 0; i < 8; i++) {
            const int row = wr * 128 + i * 16 + fg * 4;
            #pragma unroll
            for (int j = 0; j < 4; j++) {
                const int mi = wc * 64 + j * 16 + fr;
                #pragma unroll
                for (int r = 0; r < 4; r++)
                    *lgp(row + r, mi) = (_Float16)acc[i][j][r];
            }
        }
    }
    __syncthreads();
    if (wc >= 2) {
        #pragma unroll
        for (int i = 0; i < 8; i++) {
            const int row = wr * 128 + i * 16 + fg * 4;
            #pragma unroll
            for (int j = 0; j < 4; j++) {
                const int mi = (wc - 2) * 64 + j * 16 + fr;
                #pragma unroll
                for (int r = 0; r < 4; r++) {
                    float g = (float)*lgp(row + r, mi);
                    float sil = g / (1.f + __expf(-g));
                    *lgp(row + r, mi) = (_Float16)(sil * acc[i][j][r]);
                }
            }
        }
    }
    __syncthreads();
    #pragma unroll
    for (int pass = 0; pass < 8; pass++) {
        int cid = pass * 512 + tid;
        int row = cid >> 4, col8 = cid & 15;
        f16x8 v = *reinterpret_cast<const f16x8*>(
            ((row < 128) ? LgA : LgB) + (size_t)(row & 127) * 136 + col8 * 8);
        float wv = wdense[(size_t)e * 4096 + r0 + row];
        f16x8 o;
        #pragma unroll
        for (int j = 0; j < 8; j++) o[j] = (_Float16)((float)v[j] * wv);
        *reinterpret_cast<f16x8*>(ab + (size_t)(r0 + row) * 2048 + e * 128 + col8 * 8) = o;
    }
}

// ---------------------------------------------------------------- O-proj epilogue
// x2 = p0 + p1 + x (f16 partials); hm = rmsnorm(x2) * nmlp.
__global__ __launch_bounds__(256) void k_oepi(
    const _Float16* __restrict__ p0, const _Float16* __restrict__ p1,
    const float* __restrict__ x, const float* __restrict__ nmlp,
    float* __restrict__ x2, _Float16* __restrict__ hm)
{
    const int row = blockIdx.x, tid = threadIdx.x;
    const size_t base = (size_t)row * 2048 + tid * 8;
    f16x8 a = *reinterpret_cast<const f16x8*>(p0 + base);
    f16x8 b = *reinterpret_cast<const f16x8*>(p1 + base);
    float4 c0 = *reinterpret_cast<const float4*>(x + base);
    float4 c1 = *reinterpret_cast<const float4*>(x + base + 4);
    float v[8];
    v[0] = (float)a[0] + (float)b[0] + c0.x;
    v[1] = (float)a[1] + (float)b[1] + c0.y;
    v[2] = (float)a[2] + (float)b[2] + c0.z;
    v[3] = (float)a[3] + (float)b[3] + c0.w;
    v[4] = (float)a[4] + (float)b[4] + c1.x;
    v[5] = (float)a[5] + (float)b[5] + c1.y;
    v[6] = (float)a[6] + (float)b[6] + c1.z;
    v[7] = (float)a[7] + (float)b[7] + c1.w;
    float ss = 0.f;
    #pragma unroll
    for (int j = 0; j < 8; j++) ss += v[j] * v[j];
    #pragma unroll
    for (int m = 1; m < 64; m <<= 1) ss += __shfl_xor(ss, m);
    __shared__ float red[4];
    if ((tid & 63) == 0) red[tid >> 6] = ss;
    __syncthreads();
    float tot = red[0] + red[1] + red[2] + red[3];
    float r = rsqrtf(tot * (1.f / 2048.f) + 1e-6f);
    float4 o0 = { v[0], v[1], v[2], v[3] };
    float4 o1 = { v[4], v[5], v[6], v[7] };
    *reinterpret_cast<float4*>(x2 + base) = o0;
    *reinterpret_cast<float4*>(x2 + base + 4) = o1;
    float4 wa = *reinterpret_cast<const float4*>(nmlp + tid * 8);
    float4 wb = *reinterpret_cast<const float4*>(nmlp + tid * 8 + 4);
    f16x8 hv = { (_Float16)(v[0]*r*wa.x), (_Float16)(v[1]*r*wa.y),
                 (_Float16)(v[2]*r*wa.z), (_Float16)(v[3]*r*wa.w),
                 (_Float16)(v[4]*r*wb.x), (_Float16)(v[5]*r*wb.y),
                 (_Float16)(v[6]*r*wb.z), (_Float16)(v[7]*r*wb.w) };
    *reinterpret_cast<f16x8*>(hm + (size_t)row * 2048 + tid * 8) = hv;
}

// ------------------------------------------- per-head RMSNorm + RoPE + V-transpose
__global__ __launch_bounds__(256) void k_qkv_post(
    const _Float16* __restrict__ qkv,
    const float* __restrict__ cosb, const float* __restrict__ sinb,
    const float* __restrict__ qn_w, const float* __restrict__ kn_w,
    _Float16* __restrict__ qh, _Float16* __restrict__ kh,
    _Float16* __restrict__ vth)
{
    if (blockIdx.y == 9) {
        const int unit = blockIdx.x;
        if (unit >= 512) return;
        const int bkv = unit >> 5, rem = unit & 31;
        const int l0 = (rem >> 1) * 64, d0 = (rem & 1) * 64;
        const int b = bkv >> 2, kv = bkv & 3;
        __shared__ _Float16 T[64][72];
        const int t = threadIdx.x;
        const int r = t >> 3, c8 = (t & 7) * 8;
        #pragma unroll
        for (int rr = 0; rr < 2; rr++) {
            int l = l0 + r + rr * 32;
            *reinterpret_cast<f16x8*>(&T[r + rr * 32][c8]) =
                *reinterpret_cast<const f16x8*>(
                    qkv + (size_t)(b * 1024 + l) * 5120 + 4608 + kv * 128 + d0 + c8);
        }
        __syncthreads();
        #pragma unroll
        for (int rr = 0; rr < 2; rr++) {
            int d = d0 + r + rr * 32;
            f16x8 v;
            #pragma unroll
            for (int j = 0; j < 8; j++) v[j] = T[c8 + j][r + rr * 32];
            *reinterpret_cast<f16x8*>(vth + ((size_t)(bkv * 128 + d)) * 1024 + l0 + c8) = v;
        }
        return;
    }
    const int tok = blockIdx.x;
    const int u = blockIdx.y * 4 + (threadIdx.x >> 6);
    const int lane = threadIdx.x & 63;
    const int b = tok >> 10, l = tok & 1023;
    const float SCL = 0.12752887074166638f;   // 1/sqrt(128) * log2(e)
    const float c0 = cosb[(size_t)tok * 128 + lane];
    const float c1 = cosb[(size_t)tok * 128 + lane + 64];
    const float s0 = sinb[(size_t)tok * 128 + lane];
    const float s1 = sinb[(size_t)tok * 128 + lane + 64];
    if (u < 32) {
        const _Float16* base = qkv + (size_t)tok * 5120 + u * 128;
        float v0 = (float)base[lane], v1 = (float)base[lane + 64];
        float ss = v0 * v0 + v1 * v1;
        #pragma unroll
        for (int m = 1; m < 64; m <<= 1) ss += __shfl_xor(ss, m);
        float rms = rsqrtf(ss * (1.f / 128.f) + 1e-6f);
        float n0 = v0 * rms * qn_w[lane], n1 = v1 * rms * qn_w[lane + 64];
        _Float16* o = qh + (size_t)tok * 4096 + u * 128;
        o[lane]      = (_Float16)(SCL * (c0 * n0 - s0 * n1));
        o[lane + 64] = (_Float16)(SCL * (c1 * n1 + s1 * n0));
    } else {
        const int kvh = u - 32;
        const _Float16* base = qkv + (size_t)tok * 5120 + 4096 + kvh * 128;
        float v0 = (float)base[lane], v1 = (float)base[lane + 64];
        float ss = v0 * v0 + v1 * v1;
        #pragma unroll
        for (int m = 1; m < 64; m <<= 1) ss += __shfl_xor(ss, m);
        float rms = rsqrtf(ss * (1.f / 128.f) + 1e-6f);
        float n0 = v0 * rms * kn_w[lane], n1 = v1 * rms * kn_w[lane + 64];
        _Float16* o = kh + (((size_t)(b * 4 + kvh)) * 1024 + l) * 128;
        o[lane]      = (_Float16)(c0 * n0 - s0 * n1);
        o[lane + 64] = (_Float16)(c1 * n1 + s1 * n0);
    }
}

// ---------------------------------------------------------------- attention
__global__ __launch_bounds__(512) void k_attn(
    const _Float16* __restrict__ qh, const _Float16* __restrict__ kh,
    const _Float16* __restrict__ vth, const _Float16* __restrict__ ones16,
    _Float16* __restrict__ oh)
{
    const int bh = blockIdx.x;
    const int qb = 3 - blockIdx.y;
    const int b = bh >> 5, h = bh & 31, kv = h >> 3;
    const int tid = threadIdx.x, lane = tid & 63, wid = tid >> 6;
    const int fr = lane & 15, fg = lane >> 4;
    const int q0w = qb * 256 + wid * 32;

    __shared__ __align__(16) _Float16 Ks[2][64][128];
    __shared__ __align__(16) _Float16 Vs[2][128][64];
    __shared__ __align__(16) _Float16 Vones[16][64];
    __shared__ __align__(16) _Float16 Ps[8][32][72];

    const _Float16* kb = kh + ((size_t)(b * 4 + kv)) * 1024 * 128;
    const _Float16* vb = vth + ((size_t)(b * 4 + kv)) * 128 * 1024;

    auto stage = [&](int nb, int key0) {
        #pragma unroll
        for (int i = 0; i < 2; i++) {
            int rr = wid * 8 + i * 4 + (lane >> 4);
            int c16 = (lane & 15) ^ (rr & 15);
            load16_lds(kb + (size_t)(key0 + rr) * 128 + c16 * 8,
                       &Ks[nb][0][0] + (wid * 8 + i * 4) * 128);
        }
        #pragma unroll
        for (int i = 0; i < 2; i++) {
            int rr = wid * 16 + i * 8 + (lane >> 3);
            int c16 = (lane & 7) ^ (rr & 7);
            load16_lds(vb + (size_t)rr * 1024 + key0 + c16 * 8,
                       &Vs[nb][0][0] + (wid * 16 + i * 8) * 64);
        }
    };

    f16x8 aq[2][4];
    #pragma unroll
    for (int mi = 0; mi < 2; mi++) {
        const _Float16* qbase =
            qh + ((size_t)(b * 1024 + q0w + mi * 16 + fr)) * 4096 + h * 128;
        #pragma unroll
        for (int kk = 0; kk < 4; kk++)
            aq[mi][kk] = *reinterpret_cast<const f16x8*>(qbase + kk * 32 + fg * 8);
    }
    if (wid == 0) {
        #pragma unroll
        for (int i = 0; i < 2; i++)
            load16_lds(ones16 + (size_t)(lane + i * 64) * 8, &Vones[0][0] + i * 512);
    }
    stage(0, 0);

    const f32x4 z4 = { 0.f, 0.f, 0.f, 0.f };
    f32x4 oacc[2][9];
    #pragma unroll
    for (int mi = 0; mi < 2; mi++)
        #pragma unroll
        for (int dj = 0; dj < 9; dj++) oacc[mi][dj] = z4;

    const int ntiles = qb * 4 + 4;
    int cb = 0;
    for (int kt = 0; kt < ntiles; kt++) {
        const int key0 = kt * 64;
        asm volatile("s_waitcnt vmcnt(0)" ::: "memory");
        __builtin_amdgcn_s_barrier();
        if (kt + 1 < ntiles) stage(cb ^ 1, key0 + 64);

        if (key0 <= q0w + 31) {
            f32x4 sc[2][4];
            #pragma unroll
            for (int mi = 0; mi < 2; mi++)
                #pragma unroll
                for (int j = 0; j < 4; j++) sc[mi][j] = z4;
            __builtin_amdgcn_s_setprio(1);
            #pragma unroll
            for (int j = 0; j < 4; j++)
                #pragma unroll
                for (int kk = 0; kk < 4; kk++) {
                    f16x8 bk = *reinterpret_cast<const f16x8*>(
                        &Ks[cb][0][0] + (j * 16 + fr) * 128 + (((kk * 4 + fg) ^ fr) * 8));
                    #pragma unroll
                    for (int mi = 0; mi < 2; mi++)
                        sc[mi][j] = __builtin_amdgcn_mfma_f32_16x16x32_f16(
                            aq[mi][kk], bk, sc[mi][j], 0, 0, 0);
                }
            __builtin_amdgcn_s_setprio(0);

            const bool maskt = (key0 + 63 > q0w);
            #pragma unroll
            for (int mi = 0; mi < 2; mi++)
                #pragma unroll
                for (int j = 0; j < 4; j++) {
                    const int key = key0 + j * 16 + fr;
                    #pragma unroll
                    for (int r = 0; r < 4; r++) {
                        float v = sc[mi][j][r];
                        if (maskt && key > q0w + mi * 16 + fg * 4 + r) v = -1e30f;
                        Ps[wid][mi * 16 + fg * 4 + r][j * 16 + fr] =
                            (_Float16)__builtin_amdgcn_exp2f(v - 8.f);
                    }
                }

            __builtin_amdgcn_s_setprio(1);
            #pragma unroll
            for (int ks = 0; ks < 2; ks++) {
                f16x8 ap0 = *reinterpret_cast<const f16x8*>(
                    &Ps[wid][fr][ks * 32 + fg * 8]);
                f16x8 ap1 = *reinterpret_cast<const f16x8*>(
                    &Ps[wid][16 + fr][ks * 32 + fg * 8]);
                #pragma unroll
                for (int dj = 0; dj < 8; dj++) {
                    f16x8 bv = *reinterpret_cast<const f16x8*>(
                        &Vs[cb][0][0] + (dj * 16 + fr) * 64 + (((ks * 4 + fg) ^ (fr & 7)) * 8));
                    oacc[0][dj] = __builtin_amdgcn_mfma_f32_16x16x32_f16(ap0, bv, oacc[0][dj], 0, 0, 0);
                    oacc[1][dj] = __builtin_amdgcn_mfma_f32_16x16x32_f16(ap1, bv, oacc[1][dj], 0, 0, 0);
                }
                f16x8 bo = *reinterpret_cast<const f16x8*>(
                    &Vones[0][0] + fr * 64 + (((ks * 4 + fg) ^ (fr & 7)) * 8));
                oacc[0][8] = __builtin_amdgcn_mfma_f32_16x16x32_f16(ap0, bo, oacc[0][8], 0, 0, 0);
                oacc[1][8] = __builtin_amdgcn_mfma_f32_16x16x32_f16(ap1, bo, oacc[1][8], 0, 0, 0);
            }
            __builtin_amdgcn_s_setprio(0);
        }
        cb ^= 1;
    }

    #pragma unroll
    for (int mi = 0; mi < 2; mi++) {
        float inv[4];
        #pragma unroll
        for (int r = 0; r < 4; r++) {
            float l = __shfl(oacc[mi][8][r], lane & 48);
            inv[r] = 1.f / l;
        }
        #pragma unroll
        for (int dj = 0; dj < 8; dj++)
            #pragma unroll
            for (int r = 0; r < 4; r++)
                oh[((size_t)(b * 1024 + q0w + mi * 16 + fg * 4 + r)) * 4096
                   + h * 128 + dj * 16 + fr] = (_Float16)(oacc[mi][dj][r] * inv[r]);
    }
}

// ---------------------------------------------------------------- router (inline rmsnorm from x2)
__global__ __launch_bounds__(256) void k_router(
    const float* __restrict__ x2, const float* __restrict__ wm,
    const float* __restrict__ rw, float* __restrict__ wdense)
{
    const int tok = blockIdx.x * 4 + (threadIdx.x >> 6);
    const int lane = threadIdx.x & 63;
    __shared__ float lg[4][16];
    const float* hr = x2 + (size_t)tok * 2048;
    float vals[32];
    float ss = 0.f;
    #pragma unroll
    for (int i = 0; i < 32; i++) { float v = hr[i * 64 + lane]; vals[i] = v; ss += v * v; }
    #pragma unroll
    for (int m = 1; m < 64; m <<= 1) ss += __shfl_xor(ss, m);
    float r = rsqrtf(ss * (1.f / 2048.f) + 1e-6f);
    #pragma unroll
    for (int i = 0; i < 32; i++) vals[i] *= r * wm[i * 64 + lane];
    for (int e = 0; e < 16; e++) {
        float acc = 0.f;
        #pragma unroll
        for (int i = 0; i < 32; i++) acc += vals[i] * rw[(size_t)e * 2048 + i * 64 + lane];
        #pragma unroll
        for (int m = 1; m < 64; m <<= 1) acc += __shfl_xor(acc, m);
        if (lane == 0) lg[threadIdx.x >> 6][e] = acc;
    }
    __syncthreads();
    if (lane == 0) {
        float* l = lg[threadIdx.x >> 6];
        float mx = l[0];
        for (int e = 1; e < 16; e++) mx = fmaxf(mx, l[e]);
        float p[16]; float sum = 0.f;
        for (int e = 0; e < 16; e++) { p[e] = expf(l[e] - mx); sum += p[e]; }
        for (int e = 0; e < 16; e++) p[e] /= sum;
        bool sel[16]; for (int e = 0; e < 16; e++) sel[e] = false;
        float ssum = 0.f;
        for (int t = 0; t < 8; t++) {
            int bi = -1; float bv = -1.f;
            for (int e = 0; e < 16; e++) if (!sel[e] && p[e] > bv) { bv = p[e]; bi = e; }
            sel[bi] = true; ssum += bv;
        }
        for (int e = 0; e < 16; e++)
            wdense[(size_t)e * 4096 + tok] = sel[e] ? p[e] / ssum : 0.f;
    }
}

// ---------------------------------------------------------------- launch

extern "C" void kernel_launch(void* const* d_in, const int* in_sizes, int n_in,
                              void* d_out, int out_size, void* d_ws, size_t ws_size,
                              hipStream_t stream)
{
    const float* x        = (const float*)d_in[0];
    const float* cosb     = (const float*)d_in[1];
    const float* sinb     = (const float*)d_in[2];
    const float* nattn    = (const float*)d_in[3];
    const float* q_w      = (const float*)d_in[4];
    const float* k_w      = (const float*)d_in[5];
    const float* v_w      = (const float*)d_in[6];
    const float* qn_w     = (const float*)d_in[7];
    const float* kn_w     = (const float*)d_in[8];
    const float* o_w      = (const float*)d_in[9];
    const float* nmlp     = (const float*)d_in[10];
    const float* router_w = (const float*)d_in[11];
    const float* egw      = (const float*)d_in[12];
    const float* euw      = (const float*)d_in[13];
    const float* edw      = (const float*)d_in[14];

    char* w = (char*)d_ws;
    _Float16* qkvw_h = (_Float16*)(w + 0);          // 20.97 MB
    _Float16* ow_h   = (_Float16*)(w + 20971520);   // 16.78 MB
    _Float16* guw_h  = (_Float16*)(w + 37748736);   // 16.78 MB
    _Float16* dwc_h  = (_Float16*)(w + 54525952);   //  8.39 MB
    _Float16* h_h    = (_Float16*)(w + 62914560);   // 16.78 MB (aliased hm_h)
    _Float16* hm_h   = h_h;
    float*    x2     = (float*)(w + 79691776);      // 33.55 MB
    _Float16* qkv_h  = (_Float16*)(w + 113246208);  // 41.94 MB (alias o_h, ab_h)
    _Float16* o_h    = qkv_h;
    _Float16* ab_h   = qkv_h;
    _Float16* q_h    = (_Float16*)(w + 155189248);  // 33.55 MB (aliases P0/P1 f16)
    _Float16* p0_h   = (_Float16*)(w + 155189248);  // 16.78 MB
    _Float16* p1_h   = (_Float16*)(w + 172066816);  // 16.78 MB
    _Float16* k_h    = (_Float16*)(w + 188743680);  //  4.19 MB
    _Float16* vt_h   = (_Float16*)(w + 192937984);  //  4.19 MB
    float*    wdense = (float*)(w + 197132288);     //  0.26 MB
    _Float16* ones_h = (_Float16*)(w + 197394432);  //  2 KB

    k_castall<<<30721, 256, 0, stream>>>(q_w, k_w, v_w, o_w, egw, euw, edw, x, nattn,
                                         qkvw_h, ow_h, guw_h, dwc_h, ones_h, h_h);
    k_gemm8<<<dim3(16, 16), 512, 0, stream>>>(h_h, 2048, qkvw_h, 2048,
                                              qkv_h, nullptr, 5120, 2048,
                                              nullptr, nullptr);
    k_gemm<<<dim3(32, 8), 256, 0, stream>>>(h_h, 2048, qkvw_h + (size_t)4096 * 2048, 2048,
                                            nullptr, qkv_h + 4096, 5120, nullptr, 2048);
    k_qkv_post<<<dim3(4096, 10), 256, 0, stream>>>(qkv_h, cosb, sinb, qn_w, kn_w,
                                                   q_h, k_h, vt_h);
    k_attn<<<dim3(128, 4), 512, 0, stream>>>(q_h, k_h, vt_h, ones_h, o_h);
    // O-proj split-K: f16 partials P0/P1 (z selects), grid 16x8x2 = 256 blocks
    k_gemm8<<<dim3(16, 8, 2), 512, 0, stream>>>(o_h, 4096, ow_h, 4096,
                                                p0_h, p1_h, 2048, 2048,
                                                nullptr, nullptr);
    k_oepi<<<4096, 256, 0, stream>>>(p0_h, p1_h, x, nmlp, x2, hm_h);
    k_router<<<1024, 256, 0, stream>>>(x2, nmlp, router_w, wdense);
    k_gemm8<<<dim3(16, 16), 512, 0, stream>>>(hm_h, 2048, guw_h, 2048,
                                              nullptr, nullptr, 0, 2048,
                                              wdense, ab_h);
    k_gemm<<<dim3(32, 16), 256, 0, stream>>>(ab_h, 2048, dwc_h, 2048,
                                             (float*)d_out, nullptr, 2048, x2, 2048);

    (void)in_sizes; (void)n_in; (void)out_size; (void)ws_size;
}